// Round 3
// baseline (700.210 us; speedup 1.0000x reference)
//
#include <hip/hip_runtime.h>
#include <math.h>

#define NT 256
#define T_SIZE 524288u
#define T_MASK 524287u
#define PR1 2654435761u
#define PR2 805459861u

typedef float f32x64 __attribute__((ext_vector_type(64)));
typedef float f32x16 __attribute__((ext_vector_type(16)));
typedef float f32x4t __attribute__((ext_vector_type(4)));

__device__ __forceinline__ float sigmoidf_(float x) { return 1.0f / (1.0f + __expf(-x)); }
__device__ __forceinline__ float softplusf_(float x) { return fmaxf(x, 0.0f) + log1pf(__expf(-fabsf(x))); }

// acc(64) += v * wrow[0..63]   (wrow in LDS, 16B-aligned)
__device__ __forceinline__ void fma64(float v, const float* wrow, f32x64& acc) {
#pragma unroll
  for (int c = 0; c < 16; ++c) {
    f32x4t q = *reinterpret_cast<const f32x4t*>(wrow + 4 * c);
    acc[4 * c + 0] = fmaf(v, q[0], acc[4 * c + 0]);
    acc[4 * c + 1] = fmaf(v, q[1], acc[4 * c + 1]);
    acc[4 * c + 2] = fmaf(v, q[2], acc[4 * c + 2]);
    acc[4 * c + 3] = fmaf(v, q[3], acc[4 * c + 3]);
  }
}
__device__ __forceinline__ void fma16(float v, const float* wrow, f32x16& acc) {
#pragma unroll
  for (int c = 0; c < 4; ++c) {
    f32x4t q = *reinterpret_cast<const f32x4t*>(wrow + 4 * c);
    acc[4 * c + 0] = fmaf(v, q[0], acc[4 * c + 0]);
    acc[4 * c + 1] = fmaf(v, q[1], acc[4 * c + 1]);
    acc[4 * c + 2] = fmaf(v, q[2], acc[4 * c + 2]);
    acc[4 * c + 3] = fmaf(v, q[3], acc[4 * c + 3]);
  }
}
__device__ __forceinline__ void load64(const float* src, f32x64& v) {
#pragma unroll
  for (int c = 0; c < 16; ++c) {
    f32x4t q = *reinterpret_cast<const f32x4t*>(src + 4 * c);
    v[4 * c + 0] = q[0]; v[4 * c + 1] = q[1]; v[4 * c + 2] = q[2]; v[4 * c + 3] = q[3];
  }
}
__device__ __forceinline__ void load16(const float* src, f32x16& v) {
#pragma unroll
  for (int c = 0; c < 4; ++c) {
    f32x4t q = *reinterpret_cast<const f32x4t*>(src + 4 * c);
    v[4 * c + 0] = q[0]; v[4 * c + 1] = q[1]; v[4 * c + 2] = q[2]; v[4 * c + 3] = q[3];
  }
}
__device__ __forceinline__ void relu64(f32x64& v) {
#pragma unroll
  for (int i = 0; i < 64; ++i) v[i] = fmaxf(v[i], 0.f);
}

__device__ __forceinline__ void stage(float* dst, const float* __restrict__ src, int cnt, int tid) {
  for (int i = tid; i < cnt; i += NT) dst[i] = src[i];
}

// ============ K0: hash-grid encode + density net -> hv[16] (ws), static_sigma ============
extern "C" __global__ void __launch_bounds__(NT, 4) k0_density(
    const float* __restrict__ x, const float* __restrict__ tables,
    const float* __restrict__ Wd1, const float* __restrict__ bd1,
    const float* __restrict__ Wd2, const float* __restrict__ bd2,
    float* __restrict__ hvws, float* __restrict__ out, int Npts) {
  __shared__ __align__(16) float wl[3152];
  const int tid = threadIdx.x;
  const int n = blockIdx.x * NT + tid;
  stage(wl, Wd1, 2048, tid);
  stage(wl + 2048, Wd2, 1024, tid);
  stage(wl + 3072, bd1, 64, tid);
  stage(wl + 3136, bd2, 16, tid);
  __syncthreads();
  if (n >= Npts) return;

  float x0 = x[3 * n + 0], x1 = x[3 * n + 1], x2 = x[3 * n + 2];
  float xn0 = x0 * 0.25f, xn1 = x1 * 0.25f, xn2 = x2 * 0.25f;
  const bool mask = (fabsf(xn0) < 0.5f) && (fabsf(xn1) < 0.5f) && (fabsf(xn2) < 0.5f);
  xn0 += 0.5f; xn1 += 0.5f; xn2 += 0.5f;

  f32x64 hid;
  load64(wl + 3072, hid);

  const float2* tab2 = reinterpret_cast<const float2*>(tables);
  constexpr float NLV[16] = {16.f, 22.f, 30.f, 42.f, 58.f, 80.f, 111.f, 154.f,
                             213.f, 295.f, 407.f, 563.f, 777.f, 1074.f, 1483.f, 2048.f};
#pragma unroll
  for (int l = 0; l < 16; ++l) {
    const float sc = NLV[l];
    float xs0 = xn0 * sc, xs1 = xn1 * sc, xs2 = xn2 * sc;
    float f0 = floorf(xs0), f1 = floorf(xs1), f2 = floorf(xs2);
    float l0 = xs0 - f0, l1 = xs1 - f1, l2 = xs2 - f2;
    unsigned i0 = (unsigned)(int)f0, i1 = (unsigned)(int)f1, i2 = (unsigned)(int)f2;
    unsigned a0 = i0, a1 = i0 + 1u;
    unsigned b0 = i1 * PR1, b1 = (i1 + 1u) * PR1;
    unsigned c0 = i2 * PR2, c1 = (i2 + 1u) * PR2;
    const float2* tl = tab2 + (size_t)l * T_SIZE;
    float w0x = 1.f - l0, w1x = l0, w0y = 1.f - l1, w1y = l1, w0z = 1.f - l2, w1z = l2;
    float2 t0 = tl[(a0 ^ b0 ^ c0) & T_MASK];
    float2 t1 = tl[(a1 ^ b0 ^ c0) & T_MASK];
    float2 t2 = tl[(a0 ^ b1 ^ c0) & T_MASK];
    float2 t3 = tl[(a1 ^ b1 ^ c0) & T_MASK];
    float2 t4 = tl[(a0 ^ b0 ^ c1) & T_MASK];
    float2 t5 = tl[(a1 ^ b0 ^ c1) & T_MASK];
    float2 t6 = tl[(a0 ^ b1 ^ c1) & T_MASK];
    float2 t7 = tl[(a1 ^ b1 ^ c1) & T_MASK];
    float w000 = w0x * w0y * w0z, w100 = w1x * w0y * w0z;
    float w010 = w0x * w1y * w0z, w110 = w1x * w1y * w0z;
    float w001 = w0x * w0y * w1z, w101 = w1x * w0y * w1z;
    float w011 = w0x * w1y * w1z, w111 = w1x * w1y * w1z;
    float fv0 = w000 * t0.x + w100 * t1.x + w010 * t2.x + w110 * t3.x +
                w001 * t4.x + w101 * t5.x + w011 * t6.x + w111 * t7.x;
    float fv1 = w000 * t0.y + w100 * t1.y + w010 * t2.y + w110 * t3.y +
                w001 * t4.y + w101 * t5.y + w011 * t6.y + w111 * t7.y;
    fma64(fv0, wl + (2 * l + 0) * 64, hid);
    fma64(fv1, wl + (2 * l + 1) * 64, hid);
  }
  relu64(hid);
  f32x16 hv;
  load16(wl + 3136, hv);
#pragma unroll
  for (int j = 0; j < 64; ++j) fma16(hid[j], wl + 2048 + j * 16, hv);

  float4* hw = reinterpret_cast<float4*>(hvws + (size_t)n * 16);
  hw[0] = make_float4(hv[0], hv[1], hv[2], hv[3]);
  hw[1] = make_float4(hv[4], hv[5], hv[6], hv[7]);
  hw[2] = make_float4(hv[8], hv[9], hv[10], hv[11]);
  hw[3] = make_float4(hv[12], hv[13], hv[14], hv[15]);
  out[3 * (size_t)Npts + n] = mask ? __expf(hv[0]) : 0.f;
}

// ============ K1: static head ============
extern "C" __global__ void __launch_bounds__(NT, 3) k1_static(
    const float* __restrict__ x, const float* __restrict__ d,
    const int* __restrict__ aidx, const float* __restrict__ emb_a,
    const float* __restrict__ Ws1, const float* __restrict__ bs1,
    const float* __restrict__ Ws2, const float* __restrict__ bs2,
    const float* __restrict__ Ws3, const float* __restrict__ bs3,
    const float* __restrict__ hvws, float* __restrict__ out, int Npts) {
  __shared__ __align__(16) float wl[5888];
  const int tid = threadIdx.x;
  const int n = blockIdx.x * NT + tid;
  // stage A: Ws1 + bs1
  stage(wl, Ws1, 5824, tid);
  stage(wl + 5824, bs1, 64, tid);
  __syncthreads();
  const bool live = (n < Npts);
  const int nn = live ? n : 0;

  float xn0 = x[3 * nn + 0] * 0.25f, xn1 = x[3 * nn + 1] * 0.25f, xn2 = x[3 * nn + 2] * 0.25f;
  const bool mask = (fabsf(xn0) < 0.5f) && (fabsf(xn1) < 0.5f) && (fabsf(xn2) < 0.5f);

  f32x64 sa;
  load64(wl + 5824, sa);
  {
    f32x16 hv;
    load16(hvws + (size_t)nn * 16, hv);
#pragma unroll
    for (int j = 0; j < 16; ++j) fma64(hv[j], wl + j * 64, sa);
  }
  {
    float d0 = d[3 * nn + 0], d1 = d[3 * nn + 1], d2 = d[3 * nn + 2];
    fma64(d0, wl + 16 * 64, sa);
    fma64(d1, wl + 17 * 64, sa);
    fma64(d2, wl + 18 * 64, sa);
    float p = 1.f;
#pragma unroll
    for (int j = 0; j < 4; ++j) {
      fma64(__sinf(p * d0), wl + (19 + 6 * j + 0) * 64, sa);
      fma64(__sinf(p * d1), wl + (19 + 6 * j + 1) * 64, sa);
      fma64(__sinf(p * d2), wl + (19 + 6 * j + 2) * 64, sa);
      fma64(__cosf(p * d0), wl + (22 + 6 * j + 0) * 64, sa);
      fma64(__cosf(p * d1), wl + (22 + 6 * j + 1) * 64, sa);
      fma64(__cosf(p * d2), wl + (22 + 6 * j + 2) * 64, sa);
      p *= 2.f;
    }
  }
  {
    const float4* ap = reinterpret_cast<const float4*>(emb_a + (size_t)aidx[nn] * 48);
#pragma unroll
    for (int j4 = 0; j4 < 12; ++j4) {
      float4 q = ap[j4];
      fma64(q.x, wl + (43 + 4 * j4 + 0) * 64, sa);
      fma64(q.y, wl + (43 + 4 * j4 + 1) * 64, sa);
      fma64(q.z, wl + (43 + 4 * j4 + 2) * 64, sa);
      fma64(q.w, wl + (43 + 4 * j4 + 3) * 64, sa);
    }
  }
  relu64(sa);

  __syncthreads();
  // stage B: Ws2 + Ws3 + bs2 + bs3
  stage(wl, Ws2, 4096, tid);
  stage(wl + 4096, Ws3, 192, tid);
  stage(wl + 4288, bs2, 64, tid);
  if (tid < 3) wl[4352 + tid] = bs3[tid];
  __syncthreads();

  float r0 = wl[4352], r1 = wl[4353], r2 = wl[4354];
#pragma unroll
  for (int c = 0; c < 4; ++c) {
    f32x16 sbc;
    load16(wl + 4288 + 16 * c, sbc);
#pragma unroll
    for (int j = 0; j < 64; ++j) fma16(sa[j], wl + j * 64 + 16 * c, sbc);
#pragma unroll
    for (int i = 0; i < 16; ++i) {
      float v = fmaxf(sbc[i], 0.f);
      int jj = 16 * c + i;
      r0 = fmaf(v, wl[4096 + 3 * jj + 0], r0);
      r1 = fmaf(v, wl[4096 + 3 * jj + 1], r1);
      r2 = fmaf(v, wl[4096 + 3 * jj + 2], r2);
    }
  }
  if (live) {
    out[3 * (size_t)n + 0] = mask ? sigmoidf_(r0) : 0.f;
    out[3 * (size_t)n + 1] = mask ? sigmoidf_(r1) : 0.f;
    out[3 * (size_t)n + 2] = mask ? sigmoidf_(r2) : 0.f;
  }
}

// ============ K2: transient head ============
extern "C" __global__ void __launch_bounds__(NT, 3) k2_transient(
    const float* __restrict__ x, const int* __restrict__ tridx,
    const float* __restrict__ emb_t,
    const float* __restrict__ Wt1, const float* __restrict__ bt1,
    const float* __restrict__ Wt2, const float* __restrict__ bt2,
    const float* __restrict__ Wt3, const float* __restrict__ bt3,
    const float* __restrict__ Wtd, const float* __restrict__ btd,
    const float* __restrict__ Wtr, const float* __restrict__ btr,
    const float* __restrict__ Wtb, const float* __restrict__ btb,
    const float* __restrict__ hvws, float* __restrict__ out, int Npts) {
  __shared__ __align__(16) float wl[4488];
  const int tid = threadIdx.x;
  const int n = blockIdx.x * NT + tid;
  // stage A: Wt1 + bt1
  stage(wl, Wt1, 2048, tid);
  stage(wl + 2048, bt1, 64, tid);
  __syncthreads();
  const bool live = (n < Npts);
  const int nn = live ? n : 0;

  float xn0 = x[3 * nn + 0] * 0.25f, xn1 = x[3 * nn + 1] * 0.25f, xn2 = x[3 * nn + 2] * 0.25f;
  const bool mask = (fabsf(xn0) < 0.5f) && (fabsf(xn1) < 0.5f) && (fabsf(xn2) < 0.5f);

  f32x64 ta;
  load64(wl + 2048, ta);
  {
    f32x16 hv;
    load16(hvws + (size_t)nn * 16, hv);
#pragma unroll
    for (int j = 0; j < 16; ++j) fma64(hv[j], wl + j * 64, ta);
  }
  {
    const float4* tp = reinterpret_cast<const float4*>(emb_t + (size_t)tridx[nn] * 16);
#pragma unroll
    for (int j4 = 0; j4 < 4; ++j4) {
      float4 q = tp[j4];
      fma64(q.x, wl + (16 + 4 * j4 + 0) * 64, ta);
      fma64(q.y, wl + (16 + 4 * j4 + 1) * 64, ta);
      fma64(q.z, wl + (16 + 4 * j4 + 2) * 64, ta);
      fma64(q.w, wl + (16 + 4 * j4 + 3) * 64, ta);
    }
  }
  relu64(ta);

  __syncthreads();
  // stage B: Wt2 + bt2
  stage(wl, Wt2, 4096, tid);
  stage(wl + 4096, bt2, 64, tid);
  __syncthreads();

  f32x64 tb;
  load64(wl + 4096, tb);
#pragma unroll
  for (int j = 0; j < 64; ++j) fma64(ta[j], wl + j * 64, tb);
  relu64(tb);

  __syncthreads();
  // stage C: Wt3 + bt3 + heads
  stage(wl, Wt3, 4096, tid);
  stage(wl + 4096, bt3, 64, tid);
  stage(wl + 4160, Wtd, 64, tid);
  stage(wl + 4224, Wtr, 192, tid);
  stage(wl + 4416, Wtb, 64, tid);
  if (tid == 0) { wl[4480] = btd[0]; wl[4484] = btb[0]; }
  if (tid < 3) wl[4481 + tid] = btr[tid];
  __syncthreads();

  float hd = wl[4480], hr0 = wl[4481], hr1 = wl[4482], hr2 = wl[4483], hb = wl[4484];
#pragma unroll
  for (int c = 0; c < 4; ++c) {
    f32x16 tcc;
    load16(wl + 4096 + 16 * c, tcc);
#pragma unroll
    for (int j = 0; j < 64; ++j) fma16(tb[j], wl + j * 64 + 16 * c, tcc);
#pragma unroll
    for (int i = 0; i < 16; ++i) {
      float v = fmaxf(tcc[i], 0.f);
      int jj = 16 * c + i;
      hd = fmaf(v, wl[4160 + jj], hd);
      hr0 = fmaf(v, wl[4224 + 3 * jj + 0], hr0);
      hr1 = fmaf(v, wl[4224 + 3 * jj + 1], hr1);
      hr2 = fmaf(v, wl[4224 + 3 * jj + 2], hr2);
      hb = fmaf(v, wl[4416 + jj], hb);
    }
  }
  if (live) {
    size_t N4 = (size_t)Npts * 4;
    out[N4 + 3 * (size_t)n + 0] = mask ? sigmoidf_(hr0) : 0.f;
    out[N4 + 3 * (size_t)n + 1] = mask ? sigmoidf_(hr1) : 0.f;
    out[N4 + 3 * (size_t)n + 2] = mask ? sigmoidf_(hr2) : 0.f;
    out[(size_t)Npts * 7 + n] = mask ? __expf(softplusf_(hd)) : 0.f;
    out[(size_t)Npts * 8 + n] = mask ? (softplusf_(hb) + 0.1f) : 0.1f;
  }
}

extern "C" void kernel_launch(void* const* d_in, const int* in_sizes, int n_in,
                              void* d_out, int out_size, void* d_ws, size_t ws_size,
                              hipStream_t stream) {
  const int Npts = in_sizes[0] / 3;
  const float* x = (const float*)d_in[0];
  const float* d = (const float*)d_in[1];
  const int* aidx = (const int*)d_in[2];
  const int* tridx = (const int*)d_in[3];
  const float* tables = (const float*)d_in[4];
  const float* emb_a = (const float*)d_in[5];
  const float* emb_t = (const float*)d_in[6];
  const float* Wd1 = (const float*)d_in[7];
  const float* bd1 = (const float*)d_in[8];
  const float* Wd2 = (const float*)d_in[9];
  const float* bd2 = (const float*)d_in[10];
  const float* Ws1 = (const float*)d_in[11];
  const float* bs1 = (const float*)d_in[12];
  const float* Ws2 = (const float*)d_in[13];
  const float* bs2 = (const float*)d_in[14];
  const float* Ws3 = (const float*)d_in[15];
  const float* bs3 = (const float*)d_in[16];
  const float* Wt1 = (const float*)d_in[17];
  const float* bt1 = (const float*)d_in[18];
  const float* Wt2 = (const float*)d_in[19];
  const float* bt2 = (const float*)d_in[20];
  const float* Wt3 = (const float*)d_in[21];
  const float* bt3 = (const float*)d_in[22];
  const float* Wtd = (const float*)d_in[23];
  const float* btd = (const float*)d_in[24];
  const float* Wtr = (const float*)d_in[25];
  const float* btr = (const float*)d_in[26];
  const float* Wtb = (const float*)d_in[27];
  const float* btb = (const float*)d_in[28];
  float* out = (float*)d_out;
  float* hvws = (float*)d_ws;  // 16 floats per point

  int blocks = (Npts + NT - 1) / NT;
  hipLaunchKernelGGL(k0_density, dim3(blocks), dim3(NT), 0, stream,
                     x, tables, Wd1, bd1, Wd2, bd2, hvws, out, Npts);
  hipLaunchKernelGGL(k1_static, dim3(blocks), dim3(NT), 0, stream,
                     x, d, aidx, emb_a, Ws1, bs1, Ws2, bs2, Ws3, bs3, hvws, out, Npts);
  hipLaunchKernelGGL(k2_transient, dim3(blocks), dim3(NT), 0, stream,
                     x, tridx, emb_t, Wt1, bt1, Wt2, bt2, Wt3, bt3,
                     Wtd, btd, Wtr, btr, Wtb, btb, hvws, out, Npts);
}

// Round 4
// 270.365 us; speedup vs baseline: 2.5899x; 2.5899x over previous
//
#include <hip/hip_runtime.h>
#include <math.h>

#define NT 256
#define T_SIZE 524288u
#define T_MASK 524287u
#define PR1 2654435761u
#define PR2 805459861u

typedef float f32x4 __attribute__((ext_vector_type(4)));
typedef short s16x8 __attribute__((ext_vector_type(8)));

__device__ __forceinline__ float sigmoidf_(float x) { return 1.0f / (1.0f + __expf(-x)); }
__device__ __forceinline__ float softplusf_(float x) { return fmaxf(x, 0.0f) + log1pf(__expf(-fabsf(x))); }

__device__ __forceinline__ unsigned short f2bf(float f) {
  union { float f; unsigned u; } v; v.f = f;
  unsigned r = v.u + 0x7fffu + ((v.u >> 16) & 1u);
  return (unsigned short)(r >> 16);
}
__device__ __forceinline__ float bf2f(unsigned short h) {
  union { unsigned u; float f; } v; v.u = ((unsigned)h) << 16; return v.f;
}
__device__ __forceinline__ f32x4 splat4(float t) { f32x4 v; v[0]=t; v[1]=t; v[2]=t; v[3]=t; return v; }

// A-fragment load: row p = m*16+(lane&15), k = kh*32 + (lane>>4)*8 + j (j contiguous)
template <int ASTR, int SWM>
__device__ __forceinline__ s16x8 lda(const unsigned short* act, int lane, int m, int kh) {
  int p = m * 16 + (lane & 15);
  int c = (kh * 32 + ((lane >> 4) << 3)) ^ ((p & SWM) << 3);
  return *reinterpret_cast<const s16x8*>(act + p * ASTR + c);
}
// B-fragment load from frag-ordered LDS
__device__ __forceinline__ s16x8 ldb(const unsigned short* wb, int lane, int fidx) {
  return *reinterpret_cast<const s16x8*>(wb + (fidx * 64 + lane) * 8);
}
// store a bf16 pair (even col) into swizzled act row
template <int ASTR, int SWM>
__device__ __forceinline__ void stp(unsigned short* act, int p, int col, float v0, float v1) {
  unsigned pk = (unsigned)f2bf(v0) | (((unsigned)f2bf(v1)) << 16);
  *reinterpret_cast<unsigned*>(act + p * ASTR + (col ^ ((p & SWM) << 3))) = pk;
}

// stage one hi/lo plane of W[K x NCOLS] into MFMA B-fragment order
template <int KH, int NTI, int NCOLS, class F>
__device__ void stage_plane(unsigned short* dst, const float* __restrict__ W, int plane, int tid, F rowmap) {
  for (int i = tid; i < NTI * KH * 64; i += NT) {
    int f = i >> 6, lane = i & 63;
    int n = f / KH, kh = f - n * KH;
    int o = n * 16 + (lane & 15);
    int kb = kh * 32 + ((lane >> 4) << 3);
    unsigned us0, us1, us2, us3;
#define MKPAIR(dstu, j0) { \
      unsigned short e0, e1; \
      { int sr = rowmap(kb + (j0)); float w = (sr >= 0) ? W[sr * NCOLS + o] : 0.f; \
        unsigned short hi = f2bf(w); e0 = plane ? f2bf(w - bf2f(hi)) : hi; } \
      { int sr = rowmap(kb + (j0) + 1); float w = (sr >= 0) ? W[sr * NCOLS + o] : 0.f; \
        unsigned short hi = f2bf(w); e1 = plane ? f2bf(w - bf2f(hi)) : hi; } \
      dstu = (unsigned)e0 | (((unsigned)e1) << 16); }
    MKPAIR(us0, 0) MKPAIR(us1, 2) MKPAIR(us2, 4) MKPAIR(us3, 6)
#undef MKPAIR
    *reinterpret_cast<uint4*>(dst + (size_t)i * 8) = make_uint4(us0, us1, us2, us3);
  }
}

#define MFMA_(a, b, c) __builtin_amdgcn_mfma_f32_16x16x32_bf16(a, b, c, 0, 0, 0)

#define DECL_ACC f32x4 acc00, acc01, acc02, acc03, acc10, acc11, acc12, acc13, \
                       acc20, acc21, acc22, acc23, acc30, acc31, acc32, acc33;

#define ACC_INIT(B) { \
  float t0 = (B)[(lane & 15)], t1 = (B)[16 + (lane & 15)], t2 = (B)[32 + (lane & 15)], t3 = (B)[48 + (lane & 15)]; \
  acc00 = splat4(t0); acc10 = acc00; acc20 = acc00; acc30 = acc00; \
  acc01 = splat4(t1); acc11 = acc01; acc21 = acc01; acc31 = acc01; \
  acc02 = splat4(t2); acc12 = acc02; acc22 = acc02; acc32 = acc02; \
  acc03 = splat4(t3); acc13 = acc03; acc23 = acc03; acc33 = acc03; }

#define GEMM_NBLK(WPTR, kh, KH, n) { s16x8 b = ldb(WPTR, lane, (n) * (KH) + (kh)); \
  acc0##n = MFMA_(a0, b, acc0##n); acc1##n = MFMA_(a1, b, acc1##n); \
  acc2##n = MFMA_(a2, b, acc2##n); acc3##n = MFMA_(a3, b, acc3##n); }

#define GEMM64(ACTP, ASTR, SWM, WB, KH, PLN) { \
  _Pragma("unroll") for (int kh = 0; kh < (KH); ++kh) { \
    s16x8 a0 = lda<ASTR, SWM>(ACTP, lane, 0, kh), a1 = lda<ASTR, SWM>(ACTP, lane, 1, kh), \
          a2 = lda<ASTR, SWM>(ACTP, lane, 2, kh), a3 = lda<ASTR, SWM>(ACTP, lane, 3, kh); \
    _Pragma("unroll") for (int pl = 0; pl < (PLN); ++pl) { \
      const unsigned short* wp = (WB) + pl * (KH) * 2048; \
      GEMM_NBLK(wp, kh, KH, 0) GEMM_NBLK(wp, kh, KH, 1) GEMM_NBLK(wp, kh, KH, 2) GEMM_NBLK(wp, kh, KH, 3) } } }

#define ST_ACT1(ACTP, ASTR, SWM, m, n, A) { \
  _Pragma("unroll") for (int r = 0; r < 4; ++r) { \
    int p = (m) * 16 + ((lane >> 4) << 2) + r; int col = (n) * 16 + (lane & 15); \
    (ACTP)[p * (ASTR) + (col ^ ((p & (SWM)) << 3))] = f2bf(fmaxf((A)[r], 0.f)); } }

#define ST_ACT_ALL(ACTP, ASTR, SWM) \
  ST_ACT1(ACTP, ASTR, SWM, 0, 0, acc00) ST_ACT1(ACTP, ASTR, SWM, 0, 1, acc01) \
  ST_ACT1(ACTP, ASTR, SWM, 0, 2, acc02) ST_ACT1(ACTP, ASTR, SWM, 0, 3, acc03) \
  ST_ACT1(ACTP, ASTR, SWM, 1, 0, acc10) ST_ACT1(ACTP, ASTR, SWM, 1, 1, acc11) \
  ST_ACT1(ACTP, ASTR, SWM, 1, 2, acc12) ST_ACT1(ACTP, ASTR, SWM, 1, 3, acc13) \
  ST_ACT1(ACTP, ASTR, SWM, 2, 0, acc20) ST_ACT1(ACTP, ASTR, SWM, 2, 1, acc21) \
  ST_ACT1(ACTP, ASTR, SWM, 2, 2, acc22) ST_ACT1(ACTP, ASTR, SWM, 2, 3, acc23) \
  ST_ACT1(ACTP, ASTR, SWM, 3, 0, acc30) ST_ACT1(ACTP, ASTR, SWM, 3, 1, acc31) \
  ST_ACT1(ACTP, ASTR, SWM, 3, 2, acc32) ST_ACT1(ACTP, ASTR, SWM, 3, 3, acc33)

// ============ K0: hash encode + density net (MFMA) ============
extern "C" __global__ void __launch_bounds__(NT, 3) k0_density(
    const float* __restrict__ x, const float* __restrict__ tables,
    const float* __restrict__ Wd1, const float* __restrict__ bd1,
    const float* __restrict__ Wd2, const float* __restrict__ bd2,
    float* __restrict__ hvws, float* __restrict__ out, int Npts) {
  __shared__ __align__(16) unsigned short sh[22528];  // acts 16384 | Wd1 4096 | Wd2 2048
  __shared__ __align__(16) float fl[336];             // bd1 64 | bd2 16 | hv0buf 256
  const int tid = threadIdx.x, lane = tid & 63, wv = tid >> 6;
  const int n = blockIdx.x * NT + tid;
  const bool live = (n < Npts);
  const int nn = live ? n : Npts - 1;

  stage_plane<1, 4, 64>(sh + 16384, Wd1, 0, tid, [](int k) { return k; });
  stage_plane<1, 4, 64>(sh + 16384 + 2048, Wd1, 1, tid, [](int k) { return k; });
  stage_plane<2, 1, 16>(sh + 20480, Wd2, 0, tid, [](int k) { return k; });
  stage_plane<2, 1, 16>(sh + 20480 + 1024, Wd2, 1, tid, [](int k) { return k; });
  for (int i = tid; i < 64; i += NT) fl[i] = bd1[i];
  for (int i = tid; i < 16; i += NT) fl[64 + i] = bd2[i];
  __syncthreads();

  unsigned short* actw = sh + wv * 4096;
  const int p = lane;
  float x0 = x[3 * nn + 0], x1 = x[3 * nn + 1], x2 = x[3 * nn + 2];
  float xn0 = x0 * 0.25f, xn1 = x1 * 0.25f, xn2 = x2 * 0.25f;
  const bool mask = (fabsf(xn0) < 0.5f) && (fabsf(xn1) < 0.5f) && (fabsf(xn2) < 0.5f);
  xn0 += 0.5f; xn1 += 0.5f; xn2 += 0.5f;

  const float2* tab2 = reinterpret_cast<const float2*>(tables);
  constexpr float NLV[16] = {16.f, 22.f, 30.f, 42.f, 58.f, 80.f, 111.f, 154.f,
                             213.f, 295.f, 407.f, 563.f, 777.f, 1074.f, 1483.f, 2048.f};
#pragma unroll
  for (int l = 0; l < 16; ++l) {
    const float sc = NLV[l];
    float xs0 = xn0 * sc, xs1 = xn1 * sc, xs2 = xn2 * sc;
    float f0 = floorf(xs0), f1 = floorf(xs1), f2 = floorf(xs2);
    float l0 = xs0 - f0, l1 = xs1 - f1, l2 = xs2 - f2;
    unsigned i0 = (unsigned)(int)f0, i1 = (unsigned)(int)f1, i2 = (unsigned)(int)f2;
    unsigned a0 = i0, a1 = i0 + 1u;
    unsigned b0 = i1 * PR1, b1 = (i1 + 1u) * PR1;
    unsigned c0 = i2 * PR2, c1 = (i2 + 1u) * PR2;
    const float2* tl = tab2 + (size_t)l * T_SIZE;
    float w0x = 1.f - l0, w1x = l0, w0y = 1.f - l1, w1y = l1, w0z = 1.f - l2, w1z = l2;
    float2 t0 = tl[(a0 ^ b0 ^ c0) & T_MASK];
    float2 t1 = tl[(a1 ^ b0 ^ c0) & T_MASK];
    float2 t2 = tl[(a0 ^ b1 ^ c0) & T_MASK];
    float2 t3 = tl[(a1 ^ b1 ^ c0) & T_MASK];
    float2 t4 = tl[(a0 ^ b0 ^ c1) & T_MASK];
    float2 t5 = tl[(a1 ^ b0 ^ c1) & T_MASK];
    float2 t6 = tl[(a0 ^ b1 ^ c1) & T_MASK];
    float2 t7 = tl[(a1 ^ b1 ^ c1) & T_MASK];
    float w000 = w0x * w0y * w0z, w100 = w1x * w0y * w0z;
    float w010 = w0x * w1y * w0z, w110 = w1x * w1y * w0z;
    float w001 = w0x * w0y * w1z, w101 = w1x * w0y * w1z;
    float w011 = w0x * w1y * w1z, w111 = w1x * w1y * w1z;
    float fa = w000 * t0.x + w100 * t1.x + w010 * t2.x + w110 * t3.x +
               w001 * t4.x + w101 * t5.x + w011 * t6.x + w111 * t7.x;
    float fb = w000 * t0.y + w100 * t1.y + w010 * t2.y + w110 * t3.y +
               w001 * t4.y + w101 * t5.y + w011 * t6.y + w111 * t7.y;
    unsigned pk = (unsigned)f2bf(fa) | (((unsigned)f2bf(fb)) << 16);
    *reinterpret_cast<unsigned*>(actw + p * 64 + ((2 * l) ^ ((p & 7) << 3))) = pk;
  }

  DECL_ACC;
  ACC_INIT(fl);
  GEMM64(actw, 64, 7, sh + 16384, 1, 2);
  ST_ACT_ALL(actw, 64, 7);

  f32x4 h0, h1, h2, h3;
  { float t = fl[64 + (lane & 15)]; h0 = splat4(t); h1 = h0; h2 = h0; h3 = h0; }
  {
#pragma unroll
    for (int kh = 0; kh < 2; ++kh) {
      s16x8 a0 = lda<64, 7>(actw, lane, 0, kh), a1 = lda<64, 7>(actw, lane, 1, kh),
            a2 = lda<64, 7>(actw, lane, 2, kh), a3 = lda<64, 7>(actw, lane, 3, kh);
#pragma unroll
      for (int pl = 0; pl < 2; ++pl) {
        s16x8 b = ldb(sh + 20480 + pl * 1024, lane, kh);
        h0 = MFMA_(a0, b, h0); h1 = MFMA_(a1, b, h1); h2 = MFMA_(a2, b, h2); h3 = MFMA_(a3, b, h3);
      }
    }
  }
  const int ptbase = blockIdx.x * NT + wv * 64;
#define HV_ST(m, H) { _Pragma("unroll") for (int r = 0; r < 4; ++r) { \
    int pr = (m) * 16 + ((lane >> 4) << 2) + r; \
    if (ptbase + pr < Npts) hvws[(size_t)(ptbase + pr) * 16 + (lane & 15)] = (H)[r]; \
    if ((lane & 15) == 0) fl[80 + wv * 64 + pr] = (H)[r]; } }
  HV_ST(0, h0) HV_ST(1, h1) HV_ST(2, h2) HV_ST(3, h3)
#undef HV_ST
  float hv0 = fl[80 + wv * 64 + lane];
  if (live) out[3 * (size_t)Npts + n] = mask ? __expf(hv0) : 0.f;
}

// ============ K1: static head (MFMA) ============
extern "C" __global__ void __launch_bounds__(NT, 2) k1_static(
    const float* __restrict__ x, const float* __restrict__ d,
    const int* __restrict__ aidx, const float* __restrict__ emb_a,
    const float* __restrict__ Ws1, const float* __restrict__ bs1,
    const float* __restrict__ Ws2, const float* __restrict__ bs2,
    const float* __restrict__ Ws3, const float* __restrict__ bs3,
    const float* __restrict__ hvws, float* __restrict__ out, int Npts) {
  __shared__ __align__(16) unsigned short sh[30720];  // acts 24576 (4x64x96) | W plane 6144
  __shared__ __align__(16) float fl[328];             // bs1 64 | bs2 64 | Ws3 192 | bs3 3
  const int tid = threadIdx.x, lane = tid & 63, wv = tid >> 6;
  const int n = blockIdx.x * NT + tid;
  const bool live = (n < Npts);
  const int nn = live ? n : Npts - 1;
  unsigned short* actw = sh + wv * 6144;
  const int p = lane;

  float xn0 = x[3 * nn + 0] * 0.25f, xn1 = x[3 * nn + 1] * 0.25f, xn2 = x[3 * nn + 2] * 0.25f;
  const bool mask = (fabsf(xn0) < 0.5f) && (fabsf(xn1) < 0.5f) && (fabsf(xn2) < 0.5f);

  // stage this thread's activation row: hv(0..15) | emb_a(16..63) | denc(64..90) | 0(91..95)
  {
    const float4* hvp = reinterpret_cast<const float4*>(hvws + (size_t)nn * 16);
#pragma unroll
    for (int q = 0; q < 4; ++q) {
      float4 h = hvp[q];
      stp<96, 3>(actw, p, 4 * q, h.x, h.y);
      stp<96, 3>(actw, p, 4 * q + 2, h.z, h.w);
    }
    const float4* ap = reinterpret_cast<const float4*>(emb_a + (size_t)aidx[nn] * 48);
#pragma unroll
    for (int q = 0; q < 12; ++q) {
      float4 e = ap[q];
      stp<96, 3>(actw, p, 16 + 4 * q, e.x, e.y);
      stp<96, 3>(actw, p, 18 + 4 * q, e.z, e.w);
    }
    float d0 = d[3 * nn + 0], d1 = d[3 * nn + 1], d2 = d[3 * nn + 2];
    float s10 = __sinf(d0), s11 = __sinf(d1), s12 = __sinf(d2);
    float c10 = __cosf(d0), c11 = __cosf(d1), c12 = __cosf(d2);
    float s20 = __sinf(2.f * d0), s21 = __sinf(2.f * d1), s22 = __sinf(2.f * d2);
    float c20 = __cosf(2.f * d0), c21 = __cosf(2.f * d1), c22 = __cosf(2.f * d2);
    float s40 = __sinf(4.f * d0), s41 = __sinf(4.f * d1), s42 = __sinf(4.f * d2);
    float c40 = __cosf(4.f * d0), c41 = __cosf(4.f * d1), c42 = __cosf(4.f * d2);
    float s80 = __sinf(8.f * d0), s81 = __sinf(8.f * d1), s82 = __sinf(8.f * d2);
    float c80 = __cosf(8.f * d0), c81 = __cosf(8.f * d1), c82 = __cosf(8.f * d2);
    stp<96, 3>(actw, p, 64, d0, d1);   stp<96, 3>(actw, p, 66, d2, s10);
    stp<96, 3>(actw, p, 68, s11, s12); stp<96, 3>(actw, p, 70, c10, c11);
    stp<96, 3>(actw, p, 72, c12, s20); stp<96, 3>(actw, p, 74, s21, s22);
    stp<96, 3>(actw, p, 76, c20, c21); stp<96, 3>(actw, p, 78, c22, s40);
    stp<96, 3>(actw, p, 80, s41, s42); stp<96, 3>(actw, p, 82, c40, c41);
    stp<96, 3>(actw, p, 84, c42, s80); stp<96, 3>(actw, p, 86, s81, s82);
    stp<96, 3>(actw, p, 88, c80, c81); stp<96, 3>(actw, p, 90, c82, 0.f);
    stp<96, 3>(actw, p, 92, 0.f, 0.f); stp<96, 3>(actw, p, 94, 0.f, 0.f);
  }
  auto map1 = [](int k) -> int { return k < 16 ? k : (k < 64 ? 27 + k : (k < 91 ? k - 48 : -1)); };
  stage_plane<3, 4, 64>(sh + 24576, Ws1, 0, tid, map1);
  for (int i = tid; i < 64; i += NT) fl[i] = bs1[i];
  for (int i = tid; i < 64; i += NT) fl[64 + i] = bs2[i];
  for (int i = tid; i < 192; i += NT) fl[128 + i] = Ws3[i];
  if (tid < 3) fl[320 + tid] = bs3[tid];
  __syncthreads();

  DECL_ACC;
  ACC_INIT(fl);
  GEMM64(actw, 96, 3, sh + 24576, 3, 1);
  __syncthreads();
  stage_plane<3, 4, 64>(sh + 24576, Ws1, 1, tid, map1);
  __syncthreads();
  GEMM64(actw, 96, 3, sh + 24576, 3, 1);
  ST_ACT_ALL(actw, 96, 3);
  __syncthreads();
  stage_plane<2, 4, 64>(sh + 24576, Ws2, 0, tid, [](int k) { return k; });
  __syncthreads();
  ACC_INIT(fl + 64);
  GEMM64(actw, 96, 3, sh + 24576, 2, 1);
  __syncthreads();
  stage_plane<2, 4, 64>(sh + 24576, Ws2, 1, tid, [](int k) { return k; });
  __syncthreads();
  GEMM64(actw, 96, 3, sh + 24576, 2, 1);
  ST_ACT_ALL(actw, 96, 3);

  float r0 = fl[320], r1 = fl[321], r2 = fl[322];
  for (int j = 0; j < 64; ++j) {
    float a = bf2f(actw[p * 96 + (j ^ ((p & 3) << 3))]);
    r0 = fmaf(a, fl[128 + 3 * j + 0], r0);
    r1 = fmaf(a, fl[128 + 3 * j + 1], r1);
    r2 = fmaf(a, fl[128 + 3 * j + 2], r2);
  }
  if (live) {
    out[3 * (size_t)n + 0] = mask ? sigmoidf_(r0) : 0.f;
    out[3 * (size_t)n + 1] = mask ? sigmoidf_(r1) : 0.f;
    out[3 * (size_t)n + 2] = mask ? sigmoidf_(r2) : 0.f;
  }
}

// ============ K2: transient head (MFMA) ============
extern "C" __global__ void __launch_bounds__(NT, 2) k2_transient(
    const float* __restrict__ x, const int* __restrict__ tridx,
    const float* __restrict__ emb_t,
    const float* __restrict__ Wt1, const float* __restrict__ bt1,
    const float* __restrict__ Wt2, const float* __restrict__ bt2,
    const float* __restrict__ Wt3, const float* __restrict__ bt3,
    const float* __restrict__ Wtd, const float* __restrict__ btd,
    const float* __restrict__ Wtr, const float* __restrict__ btr,
    const float* __restrict__ Wtb, const float* __restrict__ btb,
    const float* __restrict__ hvws, float* __restrict__ out, int Npts) {
  __shared__ __align__(16) unsigned short sh[24576];  // acts 16384 | W region 8192
  __shared__ __align__(16) float fl[520];
  const int tid = threadIdx.x, lane = tid & 63, wv = tid >> 6;
  const int n = blockIdx.x * NT + tid;
  const bool live = (n < Npts);
  const int nn = live ? n : Npts - 1;
  unsigned short* actw = sh + wv * 4096;
  const int p = lane;

  float xn0 = x[3 * nn + 0] * 0.25f, xn1 = x[3 * nn + 1] * 0.25f, xn2 = x[3 * nn + 2] * 0.25f;
  const bool mask = (fabsf(xn0) < 0.5f) && (fabsf(xn1) < 0.5f) && (fabsf(xn2) < 0.5f);

  {
    const float4* hvp = reinterpret_cast<const float4*>(hvws + (size_t)nn * 16);
#pragma unroll
    for (int q = 0; q < 4; ++q) {
      float4 h = hvp[q];
      stp<64, 7>(actw, p, 4 * q, h.x, h.y);
      stp<64, 7>(actw, p, 4 * q + 2, h.z, h.w);
    }
    const float4* tp = reinterpret_cast<const float4*>(emb_t + (size_t)tridx[nn] * 16);
#pragma unroll
    for (int q = 0; q < 4; ++q) {
      float4 e = tp[q];
      stp<64, 7>(actw, p, 16 + 4 * q, e.x, e.y);
      stp<64, 7>(actw, p, 18 + 4 * q, e.z, e.w);
    }
  }
  stage_plane<1, 4, 64>(sh + 16384, Wt1, 0, tid, [](int k) { return k; });
  stage_plane<1, 4, 64>(sh + 16384 + 2048, Wt1, 1, tid, [](int k) { return k; });
  for (int i = tid; i < 64; i += NT) fl[i] = bt1[i];
  for (int i = tid; i < 64; i += NT) fl[64 + i] = bt2[i];
  for (int i = tid; i < 64; i += NT) fl[128 + i] = bt3[i];
  for (int i = tid; i < 64; i += NT) fl[192 + i] = Wtd[i];
  for (int i = tid; i < 192; i += NT) fl[256 + i] = Wtr[i];
  for (int i = tid; i < 64; i += NT) fl[448 + i] = Wtb[i];
  if (tid == 0) { fl[512] = btd[0]; fl[516] = btb[0]; }
  if (tid < 3) fl[513 + tid] = btr[tid];
  __syncthreads();

  DECL_ACC;
  ACC_INIT(fl);
  GEMM64(actw, 64, 7, sh + 16384, 1, 2);
  ST_ACT_ALL(actw, 64, 7);
  __syncthreads();
  stage_plane<2, 4, 64>(sh + 16384, Wt2, 0, tid, [](int k) { return k; });
  stage_plane<2, 4, 64>(sh + 16384 + 4096, Wt2, 1, tid, [](int k) { return k; });
  __syncthreads();
  ACC_INIT(fl + 64);
  GEMM64(actw, 64, 7, sh + 16384, 2, 2);
  ST_ACT_ALL(actw, 64, 7);
  __syncthreads();
  stage_plane<2, 4, 64>(sh + 16384, Wt3, 0, tid, [](int k) { return k; });
  stage_plane<2, 4, 64>(sh + 16384 + 4096, Wt3, 1, tid, [](int k) { return k; });
  __syncthreads();
  ACC_INIT(fl + 128);
  GEMM64(actw, 64, 7, sh + 16384, 2, 2);
  ST_ACT_ALL(actw, 64, 7);

  float hd = fl[512], hr0 = fl[513], hr1 = fl[514], hr2 = fl[515], hb = fl[516];
  for (int j = 0; j < 64; ++j) {
    float a = bf2f(actw[p * 64 + (j ^ ((p & 7) << 3))]);
    hd = fmaf(a, fl[192 + j], hd);
    hr0 = fmaf(a, fl[256 + 3 * j + 0], hr0);
    hr1 = fmaf(a, fl[256 + 3 * j + 1], hr1);
    hr2 = fmaf(a, fl[256 + 3 * j + 2], hr2);
    hb = fmaf(a, fl[448 + j], hb);
  }
  if (live) {
    size_t N4 = (size_t)Npts * 4;
    out[N4 + 3 * (size_t)n + 0] = mask ? sigmoidf_(hr0) : 0.f;
    out[N4 + 3 * (size_t)n + 1] = mask ? sigmoidf_(hr1) : 0.f;
    out[N4 + 3 * (size_t)n + 2] = mask ? sigmoidf_(hr2) : 0.f;
    out[(size_t)Npts * 7 + n] = mask ? __expf(softplusf_(hd)) : 0.f;
    out[(size_t)Npts * 8 + n] = mask ? (softplusf_(hb) + 0.1f) : 0.1f;
  }
}

extern "C" void kernel_launch(void* const* d_in, const int* in_sizes, int n_in,
                              void* d_out, int out_size, void* d_ws, size_t ws_size,
                              hipStream_t stream) {
  const int Npts = in_sizes[0] / 3;
  const float* x = (const float*)d_in[0];
  const float* d = (const float*)d_in[1];
  const int* aidx = (const int*)d_in[2];
  const int* tridx = (const int*)d_in[3];
  const float* tables = (const float*)d_in[4];
  const float* emb_a = (const float*)d_in[5];
  const float* emb_t = (const float*)d_in[6];
  const float* Wd1 = (const float*)d_in[7];
  const float* bd1 = (const float*)d_in[8];
  const float* Wd2 = (const float*)d_in[9];
  const float* bd2 = (const float*)d_in[10];
  const float* Ws1 = (const float*)d_in[11];
  const float* bs1 = (const float*)d_in[12];
  const float* Ws2 = (const float*)d_in[13];
  const float* bs2 = (const float*)d_in[14];
  const float* Ws3 = (const float*)d_in[15];
  const float* bs3 = (const float*)d_in[16];
  const float* Wt1 = (const float*)d_in[17];
  const float* bt1 = (const float*)d_in[18];
  const float* Wt2 = (const float*)d_in[19];
  const float* bt2 = (const float*)d_in[20];
  const float* Wt3 = (const float*)d_in[21];
  const float* bt3 = (const float*)d_in[22];
  const float* Wtd = (const float*)d_in[23];
  const float* btd = (const float*)d_in[24];
  const float* Wtr = (const float*)d_in[25];
  const float* btr = (const float*)d_in[26];
  const float* Wtb = (const float*)d_in[27];
  const float* btb = (const float*)d_in[28];
  float* out = (float*)d_out;
  float* hvws = (float*)d_ws;  // 16 f32 per point

  int blocks = (Npts + NT - 1) / NT;
  hipLaunchKernelGGL(k0_density, dim3(blocks), dim3(NT), 0, stream,
                     x, tables, Wd1, bd1, Wd2, bd2, hvws, out, Npts);
  hipLaunchKernelGGL(k1_static, dim3(blocks), dim3(NT), 0, stream,
                     x, d, aidx, emb_a, Ws1, bs1, Ws2, bs2, Ws3, bs3, hvws, out, Npts);
  hipLaunchKernelGGL(k2_transient, dim3(blocks), dim3(NT), 0, stream,
                     x, tridx, emb_t, Wt1, bt1, Wt2, bt2, Wt3, bt3,
                     Wtd, btd, Wtr, btr, Wtb, btb, hvws, out, Npts);
}

// Round 5
// 267.674 us; speedup vs baseline: 2.6159x; 1.0100x over previous
//
#include <hip/hip_runtime.h>
#include <math.h>

#define NT 256
#define NT0 512
#define T_SIZE 524288u
#define T_MASK 524287u
#define PR1 2654435761u
#define PR2 805459861u

typedef float f32x4 __attribute__((ext_vector_type(4)));
typedef short s16x8 __attribute__((ext_vector_type(8)));

__device__ __forceinline__ float sigmoidf_(float x) { return 1.0f / (1.0f + __expf(-x)); }
__device__ __forceinline__ float softplusf_(float x) { return fmaxf(x, 0.0f) + log1pf(__expf(-fabsf(x))); }

__device__ __forceinline__ unsigned short f2bf(float f) {
  union { float f; unsigned u; } v; v.f = f;
  unsigned r = v.u + 0x7fffu + ((v.u >> 16) & 1u);
  return (unsigned short)(r >> 16);
}
__device__ __forceinline__ float bf2f(unsigned short h) {
  union { unsigned u; float f; } v; v.u = ((unsigned)h) << 16; return v.f;
}
__device__ __forceinline__ f32x4 splat4(float t) { f32x4 v; v[0]=t; v[1]=t; v[2]=t; v[3]=t; return v; }

// A-fragment load: row p = m*16+(lane&15), k = kh*32 + (lane>>4)*8 + j (j contiguous)
template <int ASTR, int SWM>
__device__ __forceinline__ s16x8 lda(const unsigned short* act, int lane, int m, int kh) {
  int p = m * 16 + (lane & 15);
  int c = (kh * 32 + ((lane >> 4) << 3)) ^ ((p & SWM) << 3);
  return *reinterpret_cast<const s16x8*>(act + p * ASTR + c);
}
// B-fragment load from frag-ordered LDS
__device__ __forceinline__ s16x8 ldb(const unsigned short* wb, int lane, int fidx) {
  return *reinterpret_cast<const s16x8*>(wb + (fidx * 64 + lane) * 8);
}
// store a bf16 pair (even col) into swizzled act row
template <int ASTR, int SWM>
__device__ __forceinline__ void stp(unsigned short* act, int p, int col, float v0, float v1) {
  unsigned pk = (unsigned)f2bf(v0) | (((unsigned)f2bf(v1)) << 16);
  *reinterpret_cast<unsigned*>(act + p * ASTR + (col ^ ((p & SWM) << 3))) = pk;
}

// stage one hi/lo plane of W[K x NCOLS] into MFMA B-fragment order
template <int BT, int KH, int NTI, int NCOLS, class F>
__device__ void stage_plane(unsigned short* dst, const float* __restrict__ W, int plane, int tid, F rowmap) {
  for (int i = tid; i < NTI * KH * 64; i += BT) {
    int f = i >> 6, lane = i & 63;
    int n = f / KH, kh = f - n * KH;
    int o = n * 16 + (lane & 15);
    int kb = kh * 32 + ((lane >> 4) << 3);
    unsigned us0, us1, us2, us3;
#define MKPAIR(dstu, j0) { \
      unsigned short e0, e1; \
      { int sr = rowmap(kb + (j0)); float w = (sr >= 0) ? W[sr * NCOLS + o] : 0.f; \
        unsigned short hi = f2bf(w); e0 = plane ? f2bf(w - bf2f(hi)) : hi; } \
      { int sr = rowmap(kb + (j0) + 1); float w = (sr >= 0) ? W[sr * NCOLS + o] : 0.f; \
        unsigned short hi = f2bf(w); e1 = plane ? f2bf(w - bf2f(hi)) : hi; } \
      dstu = (unsigned)e0 | (((unsigned)e1) << 16); }
    MKPAIR(us0, 0) MKPAIR(us1, 2) MKPAIR(us2, 4) MKPAIR(us3, 6)
#undef MKPAIR
    *reinterpret_cast<uint4*>(dst + (size_t)i * 8) = make_uint4(us0, us1, us2, us3);
  }
}

template <int BT>
__device__ __forceinline__ void stage(float* dst, const float* __restrict__ src, int cnt, int tid) {
  for (int i = tid; i < cnt; i += BT) dst[i] = src[i];
}

#define MFMA_(a, b, c) __builtin_amdgcn_mfma_f32_16x16x32_bf16(a, b, c, 0, 0, 0)

#define DECL_ACC f32x4 acc00, acc01, acc02, acc03, acc10, acc11, acc12, acc13, \
                       acc20, acc21, acc22, acc23, acc30, acc31, acc32, acc33;

#define ACC_INIT(B) { \
  float t0 = (B)[(lane & 15)], t1 = (B)[16 + (lane & 15)], t2 = (B)[32 + (lane & 15)], t3 = (B)[48 + (lane & 15)]; \
  acc00 = splat4(t0); acc10 = acc00; acc20 = acc00; acc30 = acc00; \
  acc01 = splat4(t1); acc11 = acc01; acc21 = acc01; acc31 = acc01; \
  acc02 = splat4(t2); acc12 = acc02; acc22 = acc02; acc32 = acc02; \
  acc03 = splat4(t3); acc13 = acc03; acc23 = acc03; acc33 = acc03; }

#define GEMM_NBLK(WPTR, kh, KH, n) { s16x8 b = ldb(WPTR, lane, (n) * (KH) + (kh)); \
  acc0##n = MFMA_(a0, b, acc0##n); acc1##n = MFMA_(a1, b, acc1##n); \
  acc2##n = MFMA_(a2, b, acc2##n); acc3##n = MFMA_(a3, b, acc3##n); }

#define GEMM64(ACTP, ASTR, SWM, WB, KH, PLN) { \
  _Pragma("unroll") for (int kh = 0; kh < (KH); ++kh) { \
    s16x8 a0 = lda<ASTR, SWM>(ACTP, lane, 0, kh), a1 = lda<ASTR, SWM>(ACTP, lane, 1, kh), \
          a2 = lda<ASTR, SWM>(ACTP, lane, 2, kh), a3 = lda<ASTR, SWM>(ACTP, lane, 3, kh); \
    _Pragma("unroll") for (int pl = 0; pl < (PLN); ++pl) { \
      const unsigned short* wp = (WB) + pl * (KH) * 2048; \
      GEMM_NBLK(wp, kh, KH, 0) GEMM_NBLK(wp, kh, KH, 1) GEMM_NBLK(wp, kh, KH, 2) GEMM_NBLK(wp, kh, KH, 3) } } }

#define ST_ACT1(ACTP, ASTR, SWM, m, n, A) { \
  _Pragma("unroll") for (int r = 0; r < 4; ++r) { \
    int p = (m) * 16 + ((lane >> 4) << 2) + r; int col = (n) * 16 + (lane & 15); \
    (ACTP)[p * (ASTR) + (col ^ ((p & (SWM)) << 3))] = f2bf(fmaxf((A)[r], 0.f)); } }

#define ST_ACT_ALL(ACTP, ASTR, SWM) \
  ST_ACT1(ACTP, ASTR, SWM, 0, 0, acc00) ST_ACT1(ACTP, ASTR, SWM, 0, 1, acc01) \
  ST_ACT1(ACTP, ASTR, SWM, 0, 2, acc02) ST_ACT1(ACTP, ASTR, SWM, 0, 3, acc03) \
  ST_ACT1(ACTP, ASTR, SWM, 1, 0, acc10) ST_ACT1(ACTP, ASTR, SWM, 1, 1, acc11) \
  ST_ACT1(ACTP, ASTR, SWM, 1, 2, acc12) ST_ACT1(ACTP, ASTR, SWM, 1, 3, acc13) \
  ST_ACT1(ACTP, ASTR, SWM, 2, 0, acc20) ST_ACT1(ACTP, ASTR, SWM, 2, 1, acc21) \
  ST_ACT1(ACTP, ASTR, SWM, 2, 2, acc22) ST_ACT1(ACTP, ASTR, SWM, 2, 3, acc23) \
  ST_ACT1(ACTP, ASTR, SWM, 3, 0, acc30) ST_ACT1(ACTP, ASTR, SWM, 3, 1, acc31) \
  ST_ACT1(ACTP, ASTR, SWM, 3, 2, acc32) ST_ACT1(ACTP, ASTR, SWM, 3, 3, acc33)

// ============ K0: hash encode + density net (MFMA), 8 waves/block, all blocks resident ============
extern "C" __global__ void __launch_bounds__(NT0, 4) k0_density(
    const float* __restrict__ x, const float* __restrict__ tables,
    const float* __restrict__ Wd1, const float* __restrict__ bd1,
    const float* __restrict__ Wd2, const float* __restrict__ bd2,
    float* __restrict__ hvws, float* __restrict__ out, int Npts) {
  __shared__ __align__(16) unsigned short sh[38912];  // acts 32768 | Wd1 4096 | Wd2 2048
  __shared__ __align__(16) float fl[592];             // bd1 64 | bd2 16 | hv0buf 512
  const int tid = threadIdx.x, lane = tid & 63, wv = tid >> 6;
  const int n = blockIdx.x * NT0 + tid;
  const bool live = (n < Npts);
  const int nn = live ? n : Npts - 1;

  stage_plane<NT0, 1, 4, 64>(sh + 32768, Wd1, 0, tid, [](int k) { return k; });
  stage_plane<NT0, 1, 4, 64>(sh + 32768 + 2048, Wd1, 1, tid, [](int k) { return k; });
  stage_plane<NT0, 2, 1, 16>(sh + 36864, Wd2, 0, tid, [](int k) { return k; });
  stage_plane<NT0, 2, 1, 16>(sh + 36864 + 1024, Wd2, 1, tid, [](int k) { return k; });
  stage<NT0>(fl, bd1, 64, tid);
  stage<NT0>(fl + 64, bd2, 16, tid);
  __syncthreads();

  unsigned short* actw = sh + wv * 4096;
  const int p = lane;
  float x0 = x[3 * nn + 0], x1 = x[3 * nn + 1], x2 = x[3 * nn + 2];
  float xn0 = x0 * 0.25f, xn1 = x1 * 0.25f, xn2 = x2 * 0.25f;
  const bool mask = (fabsf(xn0) < 0.5f) && (fabsf(xn1) < 0.5f) && (fabsf(xn2) < 0.5f);
  xn0 += 0.5f; xn1 += 0.5f; xn2 += 0.5f;

  const float2* tab2 = reinterpret_cast<const float2*>(tables);
  constexpr float NLV[16] = {16.f, 22.f, 30.f, 42.f, 58.f, 80.f, 111.f, 154.f,
                             213.f, 295.f, 407.f, 563.f, 777.f, 1074.f, 1483.f, 2048.f};
#pragma unroll
  for (int l = 0; l < 16; ++l) {
    const float sc = NLV[l];
    float xs0 = xn0 * sc, xs1 = xn1 * sc, xs2 = xn2 * sc;
    float f0 = floorf(xs0), f1 = floorf(xs1), f2 = floorf(xs2);
    float l0 = xs0 - f0, l1 = xs1 - f1, l2 = xs2 - f2;
    unsigned i0 = (unsigned)(int)f0, i1 = (unsigned)(int)f1, i2 = (unsigned)(int)f2;
    unsigned a0 = i0, a1 = i0 + 1u;
    unsigned b0 = i1 * PR1, b1 = (i1 + 1u) * PR1;
    unsigned c0 = i2 * PR2, c1 = (i2 + 1u) * PR2;
    const float2* tl = tab2 + (size_t)l * T_SIZE;
    float w0x = 1.f - l0, w1x = l0, w0y = 1.f - l1, w1y = l1, w0z = 1.f - l2, w1z = l2;
    float2 t0 = tl[(a0 ^ b0 ^ c0) & T_MASK];
    float2 t1 = tl[(a1 ^ b0 ^ c0) & T_MASK];
    float2 t2 = tl[(a0 ^ b1 ^ c0) & T_MASK];
    float2 t3 = tl[(a1 ^ b1 ^ c0) & T_MASK];
    float2 t4 = tl[(a0 ^ b0 ^ c1) & T_MASK];
    float2 t5 = tl[(a1 ^ b0 ^ c1) & T_MASK];
    float2 t6 = tl[(a0 ^ b1 ^ c1) & T_MASK];
    float2 t7 = tl[(a1 ^ b1 ^ c1) & T_MASK];
    float w000 = w0x * w0y * w0z, w100 = w1x * w0y * w0z;
    float w010 = w0x * w1y * w0z, w110 = w1x * w1y * w0z;
    float w001 = w0x * w0y * w1z, w101 = w1x * w0y * w1z;
    float w011 = w0x * w1y * w1z, w111 = w1x * w1y * w1z;
    float fa = w000 * t0.x + w100 * t1.x + w010 * t2.x + w110 * t3.x +
               w001 * t4.x + w101 * t5.x + w011 * t6.x + w111 * t7.x;
    float fb = w000 * t0.y + w100 * t1.y + w010 * t2.y + w110 * t3.y +
               w001 * t4.y + w101 * t5.y + w011 * t6.y + w111 * t7.y;
    unsigned pk = (unsigned)f2bf(fa) | (((unsigned)f2bf(fb)) << 16);
    *reinterpret_cast<unsigned*>(actw + p * 64 + ((2 * l) ^ ((p & 7) << 3))) = pk;
  }

  DECL_ACC;
  ACC_INIT(fl);
  GEMM64(actw, 64, 7, sh + 32768, 1, 2);
  ST_ACT_ALL(actw, 64, 7);

  f32x4 h0, h1, h2, h3;
  { float t = fl[64 + (lane & 15)]; h0 = splat4(t); h1 = h0; h2 = h0; h3 = h0; }
  {
#pragma unroll
    for (int kh = 0; kh < 2; ++kh) {
      s16x8 a0 = lda<64, 7>(actw, lane, 0, kh), a1 = lda<64, 7>(actw, lane, 1, kh),
            a2 = lda<64, 7>(actw, lane, 2, kh), a3 = lda<64, 7>(actw, lane, 3, kh);
#pragma unroll
      for (int pl = 0; pl < 2; ++pl) {
        s16x8 b = ldb(sh + 36864 + pl * 1024, lane, kh);
        h0 = MFMA_(a0, b, h0); h1 = MFMA_(a1, b, h1); h2 = MFMA_(a2, b, h2); h3 = MFMA_(a3, b, h3);
      }
    }
  }
  const int ptbase = blockIdx.x * NT0 + wv * 64;
#define HV_ST(m, H) { _Pragma("unroll") for (int r = 0; r < 4; ++r) { \
    int pr = (m) * 16 + ((lane >> 4) << 2) + r; \
    if (ptbase + pr < Npts) hvws[(size_t)(ptbase + pr) * 16 + (lane & 15)] = (H)[r]; \
    if ((lane & 15) == 0) fl[80 + wv * 64 + pr] = (H)[r]; } }
  HV_ST(0, h0) HV_ST(1, h1) HV_ST(2, h2) HV_ST(3, h3)
#undef HV_ST
  float hv0 = fl[80 + wv * 64 + lane];
  if (live) out[3 * (size_t)Npts + n] = mask ? __expf(hv0) : 0.f;
}

// ============ K1: static head (MFMA), both weight planes staged at once ============
extern "C" __global__ void __launch_bounds__(NT, 2) k1_static(
    const float* __restrict__ x, const float* __restrict__ d,
    const int* __restrict__ aidx, const float* __restrict__ emb_a,
    const float* __restrict__ Ws1, const float* __restrict__ bs1,
    const float* __restrict__ Ws2, const float* __restrict__ bs2,
    const float* __restrict__ Ws3, const float* __restrict__ bs3,
    const float* __restrict__ hvws, float* __restrict__ out, int Npts) {
  __shared__ __align__(16) unsigned short sh[36864];  // acts 24576 (4x64x96) | W 12288 (2 planes)
  __shared__ __align__(16) float fl[328];             // bs1 64 | bs2 64 | Ws3 192 | bs3 3
  const int tid = threadIdx.x, lane = tid & 63, wv = tid >> 6;
  const int n = blockIdx.x * NT + tid;
  const bool live = (n < Npts);
  const int nn = live ? n : Npts - 1;
  unsigned short* actw = sh + wv * 6144;
  const int p = lane;

  float xn0 = x[3 * nn + 0] * 0.25f, xn1 = x[3 * nn + 1] * 0.25f, xn2 = x[3 * nn + 2] * 0.25f;
  const bool mask = (fabsf(xn0) < 0.5f) && (fabsf(xn1) < 0.5f) && (fabsf(xn2) < 0.5f);

  // stage this thread's activation row: hv(0..15) | emb_a(16..63) | denc(64..90) | 0(91..95)
  {
    const float4* hvp = reinterpret_cast<const float4*>(hvws + (size_t)nn * 16);
#pragma unroll
    for (int q = 0; q < 4; ++q) {
      float4 h = hvp[q];
      stp<96, 3>(actw, p, 4 * q, h.x, h.y);
      stp<96, 3>(actw, p, 4 * q + 2, h.z, h.w);
    }
    const float4* ap = reinterpret_cast<const float4*>(emb_a + (size_t)aidx[nn] * 48);
#pragma unroll
    for (int q = 0; q < 12; ++q) {
      float4 e = ap[q];
      stp<96, 3>(actw, p, 16 + 4 * q, e.x, e.y);
      stp<96, 3>(actw, p, 18 + 4 * q, e.z, e.w);
    }
    float d0 = d[3 * nn + 0], d1 = d[3 * nn + 1], d2 = d[3 * nn + 2];
    float s10 = __sinf(d0), s11 = __sinf(d1), s12 = __sinf(d2);
    float c10 = __cosf(d0), c11 = __cosf(d1), c12 = __cosf(d2);
    float s20 = __sinf(2.f * d0), s21 = __sinf(2.f * d1), s22 = __sinf(2.f * d2);
    float c20 = __cosf(2.f * d0), c21 = __cosf(2.f * d1), c22 = __cosf(2.f * d2);
    float s40 = __sinf(4.f * d0), s41 = __sinf(4.f * d1), s42 = __sinf(4.f * d2);
    float c40 = __cosf(4.f * d0), c41 = __cosf(4.f * d1), c42 = __cosf(4.f * d2);
    float s80 = __sinf(8.f * d0), s81 = __sinf(8.f * d1), s82 = __sinf(8.f * d2);
    float c80 = __cosf(8.f * d0), c81 = __cosf(8.f * d1), c82 = __cosf(8.f * d2);
    stp<96, 3>(actw, p, 64, d0, d1);   stp<96, 3>(actw, p, 66, d2, s10);
    stp<96, 3>(actw, p, 68, s11, s12); stp<96, 3>(actw, p, 70, c10, c11);
    stp<96, 3>(actw, p, 72, c12, s20); stp<96, 3>(actw, p, 74, s21, s22);
    stp<96, 3>(actw, p, 76, c20, c21); stp<96, 3>(actw, p, 78, c22, s40);
    stp<96, 3>(actw, p, 80, s41, s42); stp<96, 3>(actw, p, 82, c40, c41);
    stp<96, 3>(actw, p, 84, c42, s80); stp<96, 3>(actw, p, 86, s81, s82);
    stp<96, 3>(actw, p, 88, c80, c81); stp<96, 3>(actw, p, 90, c82, 0.f);
    stp<96, 3>(actw, p, 92, 0.f, 0.f); stp<96, 3>(actw, p, 94, 0.f, 0.f);
  }
  auto map1 = [](int k) -> int { return k < 16 ? k : (k < 64 ? 27 + k : (k < 91 ? k - 48 : -1)); };
  stage_plane<NT, 3, 4, 64>(sh + 24576, Ws1, 0, tid, map1);
  stage_plane<NT, 3, 4, 64>(sh + 24576 + 6144, Ws1, 1, tid, map1);
  stage<NT>(fl, bs1, 64, tid);
  stage<NT>(fl + 64, bs2, 64, tid);
  stage<NT>(fl + 128, Ws3, 192, tid);
  if (tid < 3) fl[320 + tid] = bs3[tid];
  __syncthreads();

  DECL_ACC;
  ACC_INIT(fl);
  GEMM64(actw, 96, 3, sh + 24576, 3, 2);
  ST_ACT_ALL(actw, 96, 3);
  __syncthreads();
  stage_plane<NT, 2, 4, 64>(sh + 24576, Ws2, 0, tid, [](int k) { return k; });
  stage_plane<NT, 2, 4, 64>(sh + 24576 + 4096, Ws2, 1, tid, [](int k) { return k; });
  __syncthreads();
  ACC_INIT(fl + 64);
  GEMM64(actw, 96, 3, sh + 24576, 2, 2);
  ST_ACT_ALL(actw, 96, 3);

  float r0 = fl[320], r1 = fl[321], r2 = fl[322];
  for (int j = 0; j < 64; ++j) {
    float a = bf2f(actw[p * 96 + (j ^ ((p & 3) << 3))]);
    r0 = fmaf(a, fl[128 + 3 * j + 0], r0);
    r1 = fmaf(a, fl[128 + 3 * j + 1], r1);
    r2 = fmaf(a, fl[128 + 3 * j + 2], r2);
  }
  if (live) {
    out[3 * (size_t)n + 0] = mask ? sigmoidf_(r0) : 0.f;
    out[3 * (size_t)n + 1] = mask ? sigmoidf_(r1) : 0.f;
    out[3 * (size_t)n + 2] = mask ? sigmoidf_(r2) : 0.f;
  }
}

// ============ K2: transient head (MFMA) ============
extern "C" __global__ void __launch_bounds__(NT, 2) k2_transient(
    const float* __restrict__ x, const int* __restrict__ tridx,
    const float* __restrict__ emb_t,
    const float* __restrict__ Wt1, const float* __restrict__ bt1,
    const float* __restrict__ Wt2, const float* __restrict__ bt2,
    const float* __restrict__ Wt3, const float* __restrict__ bt3,
    const float* __restrict__ Wtd, const float* __restrict__ btd,
    const float* __restrict__ Wtr, const float* __restrict__ btr,
    const float* __restrict__ Wtb, const float* __restrict__ btb,
    const float* __restrict__ hvws, float* __restrict__ out, int Npts) {
  __shared__ __align__(16) unsigned short sh[24576];  // acts 16384 | W region 8192
  __shared__ __align__(16) float fl[520];
  const int tid = threadIdx.x, lane = tid & 63, wv = tid >> 6;
  const int n = blockIdx.x * NT + tid;
  const bool live = (n < Npts);
  const int nn = live ? n : Npts - 1;
  unsigned short* actw = sh + wv * 4096;
  const int p = lane;

  float xn0 = x[3 * nn + 0] * 0.25f, xn1 = x[3 * nn + 1] * 0.25f, xn2 = x[3 * nn + 2] * 0.25f;
  const bool mask = (fabsf(xn0) < 0.5f) && (fabsf(xn1) < 0.5f) && (fabsf(xn2) < 0.5f);

  {
    const float4* hvp = reinterpret_cast<const float4*>(hvws + (size_t)nn * 16);
#pragma unroll
    for (int q = 0; q < 4; ++q) {
      float4 h = hvp[q];
      stp<64, 7>(actw, p, 4 * q, h.x, h.y);
      stp<64, 7>(actw, p, 4 * q + 2, h.z, h.w);
    }
    const float4* tp = reinterpret_cast<const float4*>(emb_t + (size_t)tridx[nn] * 16);
#pragma unroll
    for (int q = 0; q < 4; ++q) {
      float4 e = tp[q];
      stp<64, 7>(actw, p, 16 + 4 * q, e.x, e.y);
      stp<64, 7>(actw, p, 18 + 4 * q, e.z, e.w);
    }
  }
  stage_plane<NT, 1, 4, 64>(sh + 16384, Wt1, 0, tid, [](int k) { return k; });
  stage_plane<NT, 1, 4, 64>(sh + 16384 + 2048, Wt1, 1, tid, [](int k) { return k; });
  stage<NT>(fl, bt1, 64, tid);
  stage<NT>(fl + 64, bt2, 64, tid);
  stage<NT>(fl + 128, bt3, 64, tid);
  stage<NT>(fl + 192, Wtd, 64, tid);
  stage<NT>(fl + 256, Wtr, 192, tid);
  stage<NT>(fl + 448, Wtb, 64, tid);
  if (tid == 0) { fl[512] = btd[0]; fl[516] = btb[0]; }
  if (tid < 3) fl[513 + tid] = btr[tid];
  __syncthreads();

  DECL_ACC;
  ACC_INIT(fl);
  GEMM64(actw, 64, 7, sh + 16384, 1, 2);
  ST_ACT_ALL(actw, 64, 7);
  __syncthreads();
  stage_plane<NT, 2, 4, 64>(sh + 16384, Wt2, 0, tid, [](int k) { return k; });
  stage_plane<NT, 2, 4, 64>(sh + 16384 + 4096, Wt2, 1, tid, [](int k) { return k; });
  __syncthreads();
  ACC_INIT(fl + 64);
  GEMM64(actw, 64, 7, sh + 16384, 2, 2);
  ST_ACT_ALL(actw, 64, 7);
  __syncthreads();
  stage_plane<NT, 2, 4, 64>(sh + 16384, Wt3, 0, tid, [](int k) { return k; });
  stage_plane<NT, 2, 4, 64>(sh + 16384 + 4096, Wt3, 1, tid, [](int k) { return k; });
  __syncthreads();
  ACC_INIT(fl + 128);
  GEMM64(actw, 64, 7, sh + 16384, 2, 2);
  ST_ACT_ALL(actw, 64, 7);

  float hd = fl[512], hr0 = fl[513], hr1 = fl[514], hr2 = fl[515], hb = fl[516];
  for (int j = 0; j < 64; ++j) {
    float a = bf2f(actw[p * 64 + (j ^ ((p & 7) << 3))]);
    hd = fmaf(a, fl[192 + j], hd);
    hr0 = fmaf(a, fl[256 + 3 * j + 0], hr0);
    hr1 = fmaf(a, fl[256 + 3 * j + 1], hr1);
    hr2 = fmaf(a, fl[448 + j] * 0.f + fl[256 + 3 * j + 2], hr2);
    hb = fmaf(a, fl[448 + j], hb);
  }
  if (live) {
    size_t N4 = (size_t)Npts * 4;
    out[N4 + 3 * (size_t)n + 0] = mask ? sigmoidf_(hr0) : 0.f;
    out[N4 + 3 * (size_t)n + 1] = mask ? sigmoidf_(hr1) : 0.f;
    out[N4 + 3 * (size_t)n + 2] = mask ? sigmoidf_(hr2) : 0.f;
    out[(size_t)Npts * 7 + n] = mask ? __expf(softplusf_(hd)) : 0.f;
    out[(size_t)Npts * 8 + n] = mask ? (softplusf_(hb) + 0.1f) : 0.1f;
  }
}

extern "C" void kernel_launch(void* const* d_in, const int* in_sizes, int n_in,
                              void* d_out, int out_size, void* d_ws, size_t ws_size,
                              hipStream_t stream) {
  const int Npts = in_sizes[0] / 3;
  const float* x = (const float*)d_in[0];
  const float* d = (const float*)d_in[1];
  const int* aidx = (const int*)d_in[2];
  const int* tridx = (const int*)d_in[3];
  const float* tables = (const float*)d_in[4];
  const float* emb_a = (const float*)d_in[5];
  const float* emb_t = (const float*)d_in[6];
  const float* Wd1 = (const float*)d_in[7];
  const float* bd1 = (const float*)d_in[8];
  const float* Wd2 = (const float*)d_in[9];
  const float* bd2 = (const float*)d_in[10];
  const float* Ws1 = (const float*)d_in[11];
  const float* bs1 = (const float*)d_in[12];
  const float* Ws2 = (const float*)d_in[13];
  const float* bs2 = (const float*)d_in[14];
  const float* Ws3 = (const float*)d_in[15];
  const float* bs3 = (const float*)d_in[16];
  const float* Wt1 = (const float*)d_in[17];
  const float* bt1 = (const float*)d_in[18];
  const float* Wt2 = (const float*)d_in[19];
  const float* bt2 = (const float*)d_in[20];
  const float* Wt3 = (const float*)d_in[21];
  const float* bt3 = (const float*)d_in[22];
  const float* Wtd = (const float*)d_in[23];
  const float* btd = (const float*)d_in[24];
  const float* Wtr = (const float*)d_in[25];
  const float* btr = (const float*)d_in[26];
  const float* Wtb = (const float*)d_in[27];
  const float* btb = (const float*)d_in[28];
  float* out = (float*)d_out;
  float* hvws = (float*)d_ws;  // 16 f32 per point

  int blocks0 = (Npts + NT0 - 1) / NT0;
  int blocks = (Npts + NT - 1) / NT;
  hipLaunchKernelGGL(k0_density, dim3(blocks0), dim3(NT0), 0, stream,
                     x, tables, Wd1, bd1, Wd2, bd2, hvws, out, Npts);
  hipLaunchKernelGGL(k1_static, dim3(blocks), dim3(NT), 0, stream,
                     x, d, aidx, emb_a, Ws1, bs1, Ws2, bs2, Ws3, bs3, hvws, out, Npts);
  hipLaunchKernelGGL(k2_transient, dim3(blocks), dim3(NT), 0, stream,
                     x, tridx, emb_t, Wt1, bt1, Wt2, bt2, Wt3, bt3,
                     Wtd, btd, Wtr, btr, Wtb, btb, hvws, out, Npts);
}

// Round 6
// 244.403 us; speedup vs baseline: 2.8650x; 1.0952x over previous
//
#include <hip/hip_runtime.h>
#include <hip/hip_fp16.h>
#include <math.h>

#define NT 256
#define NT0 512
#define T_SIZE 524288u
#define T_MASK 524287u
#define PR1 2654435761u
#define PR2 805459861u

typedef float f32x4 __attribute__((ext_vector_type(4)));
typedef short s16x8 __attribute__((ext_vector_type(8)));

__device__ __forceinline__ float sigmoidf_(float x) { return 1.0f / (1.0f + __expf(-x)); }
__device__ __forceinline__ float softplusf_(float x) { return fmaxf(x, 0.0f) + log1pf(__expf(-fabsf(x))); }

__device__ __forceinline__ unsigned short f2bf(float f) {
  union { float f; unsigned u; } v; v.f = f;
  unsigned r = v.u + 0x7fffu + ((v.u >> 16) & 1u);
  return (unsigned short)(r >> 16);
}
__device__ __forceinline__ float bf2f(unsigned short h) {
  union { unsigned u; float f; } v; v.u = ((unsigned)h) << 16; return v.f;
}
__device__ __forceinline__ f32x4 splat4(float t) { f32x4 v; v[0]=t; v[1]=t; v[2]=t; v[3]=t; return v; }

// f32 -> fp8 e5m2 (via f16, RNE both steps)
__device__ __forceinline__ unsigned char f2e5(float f) {
  unsigned short u = __half_as_ushort(__float2half(f));
  return (unsigned char)(((unsigned)u + 0x7Fu + ((u >> 8) & 1u)) >> 8);
}
// fp8 e5m2 (low byte of v) -> f32
__device__ __forceinline__ float e52f(unsigned v) {
  return __half2float(__ushort_as_half((unsigned short)((v & 0xFFu) << 8)));
}

// A-fragment load: row p = m*16+(lane&15), k = kh*32 + (lane>>4)*8 + j (j contiguous)
template <int ASTR, int SWM>
__device__ __forceinline__ s16x8 lda(const unsigned short* act, int lane, int m, int kh) {
  int p = m * 16 + (lane & 15);
  int c = (kh * 32 + ((lane >> 4) << 3)) ^ ((p & SWM) << 3);
  return *reinterpret_cast<const s16x8*>(act + p * ASTR + c);
}
// B-fragment load from frag-ordered LDS
__device__ __forceinline__ s16x8 ldb(const unsigned short* wb, int lane, int fidx) {
  return *reinterpret_cast<const s16x8*>(wb + (fidx * 64 + lane) * 8);
}
// store a bf16 pair (even col) into swizzled act row
template <int ASTR, int SWM>
__device__ __forceinline__ void stp(unsigned short* act, int p, int col, float v0, float v1) {
  unsigned pk = (unsigned)f2bf(v0) | (((unsigned)f2bf(v1)) << 16);
  *reinterpret_cast<unsigned*>(act + p * ASTR + (col ^ ((p & SWM) << 3))) = pk;
}

// stage one hi/lo plane of W[K x NCOLS] into MFMA B-fragment order
template <int BT, int KH, int NTI, int NCOLS, class F>
__device__ void stage_plane(unsigned short* dst, const float* __restrict__ W, int plane, int tid, F rowmap) {
  for (int i = tid; i < NTI * KH * 64; i += BT) {
    int f = i >> 6, lane = i & 63;
    int n = f / KH, kh = f - n * KH;
    int o = n * 16 + (lane & 15);
    int kb = kh * 32 + ((lane >> 4) << 3);
    unsigned us0, us1, us2, us3;
#define MKPAIR(dstu, j0) { \
      unsigned short e0, e1; \
      { int sr = rowmap(kb + (j0)); float w = (sr >= 0) ? W[sr * NCOLS + o] : 0.f; \
        unsigned short hi = f2bf(w); e0 = plane ? f2bf(w - bf2f(hi)) : hi; } \
      { int sr = rowmap(kb + (j0) + 1); float w = (sr >= 0) ? W[sr * NCOLS + o] : 0.f; \
        unsigned short hi = f2bf(w); e1 = plane ? f2bf(w - bf2f(hi)) : hi; } \
      dstu = (unsigned)e0 | (((unsigned)e1) << 16); }
    MKPAIR(us0, 0) MKPAIR(us1, 2) MKPAIR(us2, 4) MKPAIR(us3, 6)
#undef MKPAIR
    *reinterpret_cast<uint4*>(dst + (size_t)i * 8) = make_uint4(us0, us1, us2, us3);
  }
}

template <int BT>
__device__ __forceinline__ void stage(float* dst, const float* __restrict__ src, int cnt, int tid) {
  for (int i = tid; i < cnt; i += BT) dst[i] = src[i];
}

#define MFMA_(a, b, c) __builtin_amdgcn_mfma_f32_16x16x32_bf16(a, b, c, 0, 0, 0)

#define DECL_ACC f32x4 acc00, acc01, acc02, acc03, acc10, acc11, acc12, acc13, \
                       acc20, acc21, acc22, acc23, acc30, acc31, acc32, acc33;

#define ACC_INIT(B) { \
  float t0 = (B)[(lane & 15)], t1 = (B)[16 + (lane & 15)], t2 = (B)[32 + (lane & 15)], t3 = (B)[48 + (lane & 15)]; \
  acc00 = splat4(t0); acc10 = acc00; acc20 = acc00; acc30 = acc00; \
  acc01 = splat4(t1); acc11 = acc01; acc21 = acc01; acc31 = acc01; \
  acc02 = splat4(t2); acc12 = acc02; acc22 = acc02; acc32 = acc02; \
  acc03 = splat4(t3); acc13 = acc03; acc23 = acc03; acc33 = acc03; }

#define GEMM_NBLK(WPTR, kh, KH, n) { s16x8 b = ldb(WPTR, lane, (n) * (KH) + (kh)); \
  acc0##n = MFMA_(a0, b, acc0##n); acc1##n = MFMA_(a1, b, acc1##n); \
  acc2##n = MFMA_(a2, b, acc2##n); acc3##n = MFMA_(a3, b, acc3##n); }

#define GEMM64(ACTP, ASTR, SWM, WB, KH, PLN) { \
  _Pragma("unroll") for (int kh = 0; kh < (KH); ++kh) { \
    s16x8 a0 = lda<ASTR, SWM>(ACTP, lane, 0, kh), a1 = lda<ASTR, SWM>(ACTP, lane, 1, kh), \
          a2 = lda<ASTR, SWM>(ACTP, lane, 2, kh), a3 = lda<ASTR, SWM>(ACTP, lane, 3, kh); \
    _Pragma("unroll") for (int pl = 0; pl < (PLN); ++pl) { \
      const unsigned short* wp = (WB) + pl * (KH) * 2048; \
      GEMM_NBLK(wp, kh, KH, 0) GEMM_NBLK(wp, kh, KH, 1) GEMM_NBLK(wp, kh, KH, 2) GEMM_NBLK(wp, kh, KH, 3) } } }

#define ST_ACT1(ACTP, ASTR, SWM, m, n, A) { \
  _Pragma("unroll") for (int r = 0; r < 4; ++r) { \
    int p = (m) * 16 + ((lane >> 4) << 2) + r; int col = (n) * 16 + (lane & 15); \
    (ACTP)[p * (ASTR) + (col ^ ((p & (SWM)) << 3))] = f2bf(fmaxf((A)[r], 0.f)); } }

#define ST_ACT_ALL(ACTP, ASTR, SWM) \
  ST_ACT1(ACTP, ASTR, SWM, 0, 0, acc00) ST_ACT1(ACTP, ASTR, SWM, 0, 1, acc01) \
  ST_ACT1(ACTP, ASTR, SWM, 0, 2, acc02) ST_ACT1(ACTP, ASTR, SWM, 0, 3, acc03) \
  ST_ACT1(ACTP, ASTR, SWM, 1, 0, acc10) ST_ACT1(ACTP, ASTR, SWM, 1, 1, acc11) \
  ST_ACT1(ACTP, ASTR, SWM, 1, 2, acc12) ST_ACT1(ACTP, ASTR, SWM, 1, 3, acc13) \
  ST_ACT1(ACTP, ASTR, SWM, 2, 0, acc20) ST_ACT1(ACTP, ASTR, SWM, 2, 1, acc21) \
  ST_ACT1(ACTP, ASTR, SWM, 2, 2, acc22) ST_ACT1(ACTP, ASTR, SWM, 2, 3, acc23) \
  ST_ACT1(ACTP, ASTR, SWM, 3, 0, acc30) ST_ACT1(ACTP, ASTR, SWM, 3, 1, acc31) \
  ST_ACT1(ACTP, ASTR, SWM, 3, 2, acc32) ST_ACT1(ACTP, ASTR, SWM, 3, 3, acc33)

// ============ Kconv: f32 table -> fp8 e5m2 table (2 entries = 4 fp8 per thread) ============
__global__ void __launch_bounds__(256) kconv(const float* __restrict__ tables,
                                             unsigned* __restrict__ t8, int nq) {
  int i = blockIdx.x * 256 + threadIdx.x;
  if (i >= nq) return;
  float4 v = reinterpret_cast<const float4*>(tables)[i];
  t8[i] = (unsigned)f2e5(v.x) | ((unsigned)f2e5(v.y) << 8) |
          ((unsigned)f2e5(v.z) << 16) | ((unsigned)f2e5(v.w) << 24);
}

// ============ K0: hash encode + density net (MFMA) ============
template <int F8>
__global__ void __launch_bounds__(NT0, 4) k0_density(
    const float* __restrict__ x, const float* __restrict__ tables,
    const unsigned short* __restrict__ t8,
    const float* __restrict__ Wd1, const float* __restrict__ bd1,
    const float* __restrict__ Wd2, const float* __restrict__ bd2,
    float* __restrict__ hvws, float* __restrict__ out, int Npts) {
  __shared__ __align__(16) unsigned short sh[38912];  // acts 32768 | Wd1 4096 | Wd2 2048
  __shared__ __align__(16) float fl[592];             // bd1 64 | bd2 16 | hv0buf 512
  const int tid = threadIdx.x, lane = tid & 63, wv = tid >> 6;
  const int n = blockIdx.x * NT0 + tid;
  const bool live = (n < Npts);
  const int nn = live ? n : Npts - 1;

  stage_plane<NT0, 1, 4, 64>(sh + 32768, Wd1, 0, tid, [](int k) { return k; });
  stage_plane<NT0, 1, 4, 64>(sh + 32768 + 2048, Wd1, 1, tid, [](int k) { return k; });
  stage_plane<NT0, 2, 1, 16>(sh + 36864, Wd2, 0, tid, [](int k) { return k; });
  stage_plane<NT0, 2, 1, 16>(sh + 36864 + 1024, Wd2, 1, tid, [](int k) { return k; });
  stage<NT0>(fl, bd1, 64, tid);
  stage<NT0>(fl + 64, bd2, 16, tid);
  __syncthreads();

  unsigned short* actw = sh + wv * 4096;
  const int p = lane;
  float x0 = x[3 * nn + 0], x1 = x[3 * nn + 1], x2 = x[3 * nn + 2];
  float xn0 = x0 * 0.25f, xn1 = x1 * 0.25f, xn2 = x2 * 0.25f;
  const bool mask = (fabsf(xn0) < 0.5f) && (fabsf(xn1) < 0.5f) && (fabsf(xn2) < 0.5f);
  xn0 += 0.5f; xn1 += 0.5f; xn2 += 0.5f;

  const float2* tab2 = reinterpret_cast<const float2*>(tables);
  constexpr float NLV[16] = {16.f, 22.f, 30.f, 42.f, 58.f, 80.f, 111.f, 154.f,
                             213.f, 295.f, 407.f, 563.f, 777.f, 1074.f, 1483.f, 2048.f};
#pragma unroll
  for (int l = 0; l < 16; ++l) {
    const float sc = NLV[l];
    float xs0 = xn0 * sc, xs1 = xn1 * sc, xs2 = xn2 * sc;
    float f0 = floorf(xs0), f1 = floorf(xs1), f2 = floorf(xs2);
    float l0 = xs0 - f0, l1 = xs1 - f1, l2 = xs2 - f2;
    unsigned i0 = (unsigned)(int)f0, i1 = (unsigned)(int)f1, i2 = (unsigned)(int)f2;
    unsigned a0 = i0, a1 = i0 + 1u;
    unsigned b0 = i1 * PR1, b1 = (i1 + 1u) * PR1;
    unsigned c0 = i2 * PR2, c1 = (i2 + 1u) * PR2;
    float w0x = 1.f - l0, w1x = l0, w0y = 1.f - l1, w1y = l1, w0z = 1.f - l2, w1z = l2;
    float2 t0, t1, t2, t3, t4, t5, t6, t7;
    if constexpr (F8) {
      const unsigned short* tl8 = t8 + (size_t)l * T_SIZE;
      unsigned short q0 = tl8[(a0 ^ b0 ^ c0) & T_MASK];
      unsigned short q1 = tl8[(a1 ^ b0 ^ c0) & T_MASK];
      unsigned short q2 = tl8[(a0 ^ b1 ^ c0) & T_MASK];
      unsigned short q3 = tl8[(a1 ^ b1 ^ c0) & T_MASK];
      unsigned short q4 = tl8[(a0 ^ b0 ^ c1) & T_MASK];
      unsigned short q5 = tl8[(a1 ^ b0 ^ c1) & T_MASK];
      unsigned short q6 = tl8[(a0 ^ b1 ^ c1) & T_MASK];
      unsigned short q7 = tl8[(a1 ^ b1 ^ c1) & T_MASK];
      t0 = make_float2(e52f(q0), e52f(q0 >> 8));
      t1 = make_float2(e52f(q1), e52f(q1 >> 8));
      t2 = make_float2(e52f(q2), e52f(q2 >> 8));
      t3 = make_float2(e52f(q3), e52f(q3 >> 8));
      t4 = make_float2(e52f(q4), e52f(q4 >> 8));
      t5 = make_float2(e52f(q5), e52f(q5 >> 8));
      t6 = make_float2(e52f(q6), e52f(q6 >> 8));
      t7 = make_float2(e52f(q7), e52f(q7 >> 8));
    } else {
      const float2* tl = tab2 + (size_t)l * T_SIZE;
      t0 = tl[(a0 ^ b0 ^ c0) & T_MASK];
      t1 = tl[(a1 ^ b0 ^ c0) & T_MASK];
      t2 = tl[(a0 ^ b1 ^ c0) & T_MASK];
      t3 = tl[(a1 ^ b1 ^ c0) & T_MASK];
      t4 = tl[(a0 ^ b0 ^ c1) & T_MASK];
      t5 = tl[(a1 ^ b0 ^ c1) & T_MASK];
      t6 = tl[(a0 ^ b1 ^ c1) & T_MASK];
      t7 = tl[(a1 ^ b1 ^ c1) & T_MASK];
    }
    float w000 = w0x * w0y * w0z, w100 = w1x * w0y * w0z;
    float w010 = w0x * w1y * w0z, w110 = w1x * w1y * w0z;
    float w001 = w0x * w0y * w1z, w101 = w1x * w0y * w1z;
    float w011 = w0x * w1y * w1z, w111 = w1x * w1y * w1z;
    float fa = w000 * t0.x + w100 * t1.x + w010 * t2.x + w110 * t3.x +
               w001 * t4.x + w101 * t5.x + w011 * t6.x + w111 * t7.x;
    float fb = w000 * t0.y + w100 * t1.y + w010 * t2.y + w110 * t3.y +
               w001 * t4.y + w101 * t5.y + w011 * t6.y + w111 * t7.y;
    unsigned pk = (unsigned)f2bf(fa) | (((unsigned)f2bf(fb)) << 16);
    *reinterpret_cast<unsigned*>(actw + p * 64 + ((2 * l) ^ ((p & 7) << 3))) = pk;
  }

  DECL_ACC;
  ACC_INIT(fl);
  GEMM64(actw, 64, 7, sh + 32768, 1, 2);
  ST_ACT_ALL(actw, 64, 7);

  f32x4 h0, h1, h2, h3;
  { float t = fl[64 + (lane & 15)]; h0 = splat4(t); h1 = h0; h2 = h0; h3 = h0; }
  {
#pragma unroll
    for (int kh = 0; kh < 2; ++kh) {
      s16x8 a0 = lda<64, 7>(actw, lane, 0, kh), a1 = lda<64, 7>(actw, lane, 1, kh),
            a2 = lda<64, 7>(actw, lane, 2, kh), a3 = lda<64, 7>(actw, lane, 3, kh);
#pragma unroll
      for (int pl = 0; pl < 2; ++pl) {
        s16x8 b = ldb(sh + 36864 + pl * 1024, lane, kh);
        h0 = MFMA_(a0, b, h0); h1 = MFMA_(a1, b, h1); h2 = MFMA_(a2, b, h2); h3 = MFMA_(a3, b, h3);
      }
    }
  }
  const int ptbase = blockIdx.x * NT0 + wv * 64;
#define HV_ST(m, H) { _Pragma("unroll") for (int r = 0; r < 4; ++r) { \
    int pr = (m) * 16 + ((lane >> 4) << 2) + r; \
    if (ptbase + pr < Npts) hvws[(size_t)(ptbase + pr) * 16 + (lane & 15)] = (H)[r]; \
    if ((lane & 15) == 0) fl[80 + wv * 64 + pr] = (H)[r]; } }
  HV_ST(0, h0) HV_ST(1, h1) HV_ST(2, h2) HV_ST(3, h3)
#undef HV_ST
  float hv0 = fl[80 + wv * 64 + lane];
  if (live) out[3 * (size_t)Npts + n] = mask ? __expf(hv0) : 0.f;
}

// ============ K1: static head (MFMA) ============
__global__ void __launch_bounds__(NT, 2) k1_static(
    const float* __restrict__ x, const float* __restrict__ d,
    const int* __restrict__ aidx, const float* __restrict__ emb_a,
    const float* __restrict__ Ws1, const float* __restrict__ bs1,
    const float* __restrict__ Ws2, const float* __restrict__ bs2,
    const float* __restrict__ Ws3, const float* __restrict__ bs3,
    const float* __restrict__ hvws, float* __restrict__ out, int Npts) {
  __shared__ __align__(16) unsigned short sh[36864];  // acts 24576 (4x64x96) | W 12288 (2 planes)
  __shared__ __align__(16) float fl[328];             // bs1 64 | bs2 64 | Ws3 192 | bs3 3
  const int tid = threadIdx.x, lane = tid & 63, wv = tid >> 6;
  const int n = blockIdx.x * NT + tid;
  const bool live = (n < Npts);
  const int nn = live ? n : Npts - 1;
  unsigned short* actw = sh + wv * 6144;
  const int p = lane;

  float xn0 = x[3 * nn + 0] * 0.25f, xn1 = x[3 * nn + 1] * 0.25f, xn2 = x[3 * nn + 2] * 0.25f;
  const bool mask = (fabsf(xn0) < 0.5f) && (fabsf(xn1) < 0.5f) && (fabsf(xn2) < 0.5f);

  {
    const float4* hvp = reinterpret_cast<const float4*>(hvws + (size_t)nn * 16);
#pragma unroll
    for (int q = 0; q < 4; ++q) {
      float4 h = hvp[q];
      stp<96, 3>(actw, p, 4 * q, h.x, h.y);
      stp<96, 3>(actw, p, 4 * q + 2, h.z, h.w);
    }
    const float4* ap = reinterpret_cast<const float4*>(emb_a + (size_t)aidx[nn] * 48);
#pragma unroll
    for (int q = 0; q < 12; ++q) {
      float4 e = ap[q];
      stp<96, 3>(actw, p, 16 + 4 * q, e.x, e.y);
      stp<96, 3>(actw, p, 18 + 4 * q, e.z, e.w);
    }
    float d0 = d[3 * nn + 0], d1 = d[3 * nn + 1], d2 = d[3 * nn + 2];
    float s10 = __sinf(d0), s11 = __sinf(d1), s12 = __sinf(d2);
    float c10 = __cosf(d0), c11 = __cosf(d1), c12 = __cosf(d2);
    float s20 = __sinf(2.f * d0), s21 = __sinf(2.f * d1), s22 = __sinf(2.f * d2);
    float c20 = __cosf(2.f * d0), c21 = __cosf(2.f * d1), c22 = __cosf(2.f * d2);
    float s40 = __sinf(4.f * d0), s41 = __sinf(4.f * d1), s42 = __sinf(4.f * d2);
    float c40 = __cosf(4.f * d0), c41 = __cosf(4.f * d1), c42 = __cosf(4.f * d2);
    float s80 = __sinf(8.f * d0), s81 = __sinf(8.f * d1), s82 = __sinf(8.f * d2);
    float c80 = __cosf(8.f * d0), c81 = __cosf(8.f * d1), c82 = __cosf(8.f * d2);
    stp<96, 3>(actw, p, 64, d0, d1);   stp<96, 3>(actw, p, 66, d2, s10);
    stp<96, 3>(actw, p, 68, s11, s12); stp<96, 3>(actw, p, 70, c10, c11);
    stp<96, 3>(actw, p, 72, c12, s20); stp<96, 3>(actw, p, 74, s21, s22);
    stp<96, 3>(actw, p, 76, c20, c21); stp<96, 3>(actw, p, 78, c22, s40);
    stp<96, 3>(actw, p, 80, s41, s42); stp<96, 3>(actw, p, 82, c40, c41);
    stp<96, 3>(actw, p, 84, c42, s80); stp<96, 3>(actw, p, 86, s81, s82);
    stp<96, 3>(actw, p, 88, c80, c81); stp<96, 3>(actw, p, 90, c82, 0.f);
    stp<96, 3>(actw, p, 92, 0.f, 0.f); stp<96, 3>(actw, p, 94, 0.f, 0.f);
  }
  auto map1 = [](int k) -> int { return k < 16 ? k : (k < 64 ? 27 + k : (k < 91 ? k - 48 : -1)); };
  stage_plane<NT, 3, 4, 64>(sh + 24576, Ws1, 0, tid, map1);
  stage_plane<NT, 3, 4, 64>(sh + 24576 + 6144, Ws1, 1, tid, map1);
  stage<NT>(fl, bs1, 64, tid);
  stage<NT>(fl + 64, bs2, 64, tid);
  stage<NT>(fl + 128, Ws3, 192, tid);
  if (tid < 3) fl[320 + tid] = bs3[tid];
  __syncthreads();

  DECL_ACC;
  ACC_INIT(fl);
  GEMM64(actw, 96, 3, sh + 24576, 3, 2);
  ST_ACT_ALL(actw, 96, 3);
  __syncthreads();
  stage_plane<NT, 2, 4, 64>(sh + 24576, Ws2, 0, tid, [](int k) { return k; });
  stage_plane<NT, 2, 4, 64>(sh + 24576 + 4096, Ws2, 1, tid, [](int k) { return k; });
  __syncthreads();
  ACC_INIT(fl + 64);
  GEMM64(actw, 96, 3, sh + 24576, 2, 2);
  ST_ACT_ALL(actw, 96, 3);

  float r0 = fl[320], r1 = fl[321], r2 = fl[322];
  for (int j = 0; j < 64; ++j) {
    float a = bf2f(actw[p * 96 + (j ^ ((p & 3) << 3))]);
    r0 = fmaf(a, fl[128 + 3 * j + 0], r0);
    r1 = fmaf(a, fl[128 + 3 * j + 1], r1);
    r2 = fmaf(a, fl[128 + 3 * j + 2], r2);
  }
  if (live) {
    out[3 * (size_t)n + 0] = mask ? sigmoidf_(r0) : 0.f;
    out[3 * (size_t)n + 1] = mask ? sigmoidf_(r1) : 0.f;
    out[3 * (size_t)n + 2] = mask ? sigmoidf_(r2) : 0.f;
  }
}

// ============ K2: transient head (MFMA) ============
__global__ void __launch_bounds__(NT, 2) k2_transient(
    const float* __restrict__ x, const int* __restrict__ tridx,
    const float* __restrict__ emb_t,
    const float* __restrict__ Wt1, const float* __restrict__ bt1,
    const float* __restrict__ Wt2, const float* __restrict__ bt2,
    const float* __restrict__ Wt3, const float* __restrict__ bt3,
    const float* __restrict__ Wtd, const float* __restrict__ btd,
    const float* __restrict__ Wtr, const float* __restrict__ btr,
    const float* __restrict__ Wtb, const float* __restrict__ btb,
    const float* __restrict__ hvws, float* __restrict__ out, int Npts) {
  __shared__ __align__(16) unsigned short sh[24576];  // acts 16384 | W region 8192
  __shared__ __align__(16) float fl[520];
  const int tid = threadIdx.x, lane = tid & 63, wv = tid >> 6;
  const int n = blockIdx.x * NT + tid;
  const bool live = (n < Npts);
  const int nn = live ? n : Npts - 1;
  unsigned short* actw = sh + wv * 4096;
  const int p = lane;

  float xn0 = x[3 * nn + 0] * 0.25f, xn1 = x[3 * nn + 1] * 0.25f, xn2 = x[3 * nn + 2] * 0.25f;
  const bool mask = (fabsf(xn0) < 0.5f) && (fabsf(xn1) < 0.5f) && (fabsf(xn2) < 0.5f);

  {
    const float4* hvp = reinterpret_cast<const float4*>(hvws + (size_t)nn * 16);
#pragma unroll
    for (int q = 0; q < 4; ++q) {
      float4 h = hvp[q];
      stp<64, 7>(actw, p, 4 * q, h.x, h.y);
      stp<64, 7>(actw, p, 4 * q + 2, h.z, h.w);
    }
    const float4* tp = reinterpret_cast<const float4*>(emb_t + (size_t)tridx[nn] * 16);
#pragma unroll
    for (int q = 0; q < 4; ++q) {
      float4 e = tp[q];
      stp<64, 7>(actw, p, 16 + 4 * q, e.x, e.y);
      stp<64, 7>(actw, p, 18 + 4 * q, e.z, e.w);
    }
  }
  stage_plane<NT, 1, 4, 64>(sh + 16384, Wt1, 0, tid, [](int k) { return k; });
  stage_plane<NT, 1, 4, 64>(sh + 16384 + 2048, Wt1, 1, tid, [](int k) { return k; });
  stage<NT>(fl, bt1, 64, tid);
  stage<NT>(fl + 64, bt2, 64, tid);
  stage<NT>(fl + 128, bt3, 64, tid);
  stage<NT>(fl + 192, Wtd, 64, tid);
  stage<NT>(fl + 256, Wtr, 192, tid);
  stage<NT>(fl + 448, Wtb, 64, tid);
  if (tid == 0) { fl[512] = btd[0]; fl[516] = btb[0]; }
  if (tid < 3) fl[513 + tid] = btr[tid];
  __syncthreads();

  DECL_ACC;
  ACC_INIT(fl);
  GEMM64(actw, 64, 7, sh + 16384, 1, 2);
  ST_ACT_ALL(actw, 64, 7);
  __syncthreads();
  stage_plane<NT, 2, 4, 64>(sh + 16384, Wt2, 0, tid, [](int k) { return k; });
  stage_plane<NT, 2, 4, 64>(sh + 16384 + 4096, Wt2, 1, tid, [](int k) { return k; });
  __syncthreads();
  ACC_INIT(fl + 64);
  GEMM64(actw, 64, 7, sh + 16384, 2, 2);
  ST_ACT_ALL(actw, 64, 7);
  __syncthreads();
  stage_plane<NT, 2, 4, 64>(sh + 16384, Wt3, 0, tid, [](int k) { return k; });
  stage_plane<NT, 2, 4, 64>(sh + 16384 + 4096, Wt3, 1, tid, [](int k) { return k; });
  __syncthreads();
  ACC_INIT(fl + 128);
  GEMM64(actw, 64, 7, sh + 16384, 2, 2);
  ST_ACT_ALL(actw, 64, 7);

  float hd = fl[512], hr0 = fl[513], hr1 = fl[514], hr2 = fl[515], hb = fl[516];
  for (int j = 0; j < 64; ++j) {
    float a = bf2f(actw[p * 64 + (j ^ ((p & 7) << 3))]);
    hd = fmaf(a, fl[192 + j], hd);
    hr0 = fmaf(a, fl[256 + 3 * j + 0], hr0);
    hr1 = fmaf(a, fl[256 + 3 * j + 1], hr1);
    hr2 = fmaf(a, fl[256 + 3 * j + 2], hr2);
    hb = fmaf(a, fl[448 + j], hb);
  }
  if (live) {
    size_t N4 = (size_t)Npts * 4;
    out[N4 + 3 * (size_t)n + 0] = mask ? sigmoidf_(hr0) : 0.f;
    out[N4 + 3 * (size_t)n + 1] = mask ? sigmoidf_(hr1) : 0.f;
    out[N4 + 3 * (size_t)n + 2] = mask ? sigmoidf_(hr2) : 0.f;
    out[(size_t)Npts * 7 + n] = mask ? __expf(softplusf_(hd)) : 0.f;
    out[(size_t)Npts * 8 + n] = mask ? (softplusf_(hb) + 0.1f) : 0.1f;
  }
}

extern "C" void kernel_launch(void* const* d_in, const int* in_sizes, int n_in,
                              void* d_out, int out_size, void* d_ws, size_t ws_size,
                              hipStream_t stream) {
  const int Npts = in_sizes[0] / 3;
  const float* x = (const float*)d_in[0];
  const float* d = (const float*)d_in[1];
  const int* aidx = (const int*)d_in[2];
  const int* tridx = (const int*)d_in[3];
  const float* tables = (const float*)d_in[4];
  const float* emb_a = (const float*)d_in[5];
  const float* emb_t = (const float*)d_in[6];
  const float* Wd1 = (const float*)d_in[7];
  const float* bd1 = (const float*)d_in[8];
  const float* Wd2 = (const float*)d_in[9];
  const float* bd2 = (const float*)d_in[10];
  const float* Ws1 = (const float*)d_in[11];
  const float* bs1 = (const float*)d_in[12];
  const float* Ws2 = (const float*)d_in[13];
  const float* bs2 = (const float*)d_in[14];
  const float* Ws3 = (const float*)d_in[15];
  const float* bs3 = (const float*)d_in[16];
  const float* Wt1 = (const float*)d_in[17];
  const float* bt1 = (const float*)d_in[18];
  const float* Wt2 = (const float*)d_in[19];
  const float* bt2 = (const float*)d_in[20];
  const float* Wt3 = (const float*)d_in[21];
  const float* bt3 = (const float*)d_in[22];
  const float* Wtd = (const float*)d_in[23];
  const float* btd = (const float*)d_in[24];
  const float* Wtr = (const float*)d_in[25];
  const float* btr = (const float*)d_in[26];
  const float* Wtb = (const float*)d_in[27];
  const float* btb = (const float*)d_in[28];
  float* out = (float*)d_out;
  float* hvws = (float*)d_ws;  // 16 f32 per point
  size_t hv_bytes = (size_t)Npts * 16 * sizeof(float);
  unsigned short* t8 = (unsigned short*)((char*)d_ws + hv_bytes);
  const size_t t8_bytes = (size_t)16 * T_SIZE * 2;  // 16.8 MB
  const bool use8 = (ws_size >= hv_bytes + t8_bytes);

  int blocks0 = (Npts + NT0 - 1) / NT0;
  int blocks = (Npts + NT - 1) / NT;
  if (use8) {
    int nq = (int)(16 * T_SIZE / 2);  // uints (2 entries each)
    kconv<<<dim3((nq + 255) / 256), dim3(256), 0, stream>>>(tables, (unsigned*)t8, nq);
    k0_density<1><<<dim3(blocks0), dim3(NT0), 0, stream>>>(
        x, tables, t8, Wd1, bd1, Wd2, bd2, hvws, out, Npts);
  } else {
    k0_density<0><<<dim3(blocks0), dim3(NT0), 0, stream>>>(
        x, tables, t8, Wd1, bd1, Wd2, bd2, hvws, out, Npts);
  }
  k1_static<<<dim3(blocks), dim3(NT), 0, stream>>>(
      x, d, aidx, emb_a, Ws1, bs1, Ws2, bs2, Ws3, bs3, hvws, out, Npts);
  k2_transient<<<dim3(blocks), dim3(NT), 0, stream>>>(
      x, tridx, emb_t, Wt1, bt1, Wt2, bt2, Wt3, bt3,
      Wtd, btd, Wtr, btr, Wtb, btb, hvws, out, Npts);
}